// Round 1
// baseline (4770.061 us; speedup 1.0000x reference)
//
#include <hip/hip_runtime.h>

#define EPS 1e-5f
#define SLOPE 0.01f
#define STAT_BLOCKS 240

static inline int cdiv(long a, int b) { return (int)((a + b - 1) / b); }

// ---------- degree / normalization ----------
__global__ void deg_kernel(const int* __restrict__ dst, int* __restrict__ degi, int E) {
  int e = blockIdx.x * 256 + threadIdx.x;
  if (e < E) atomicAdd(&degi[dst[e]], 1);
}

__global__ void dinv_kernel(const int* __restrict__ degi, float* __restrict__ dinv, int n) {
  int v = blockIdx.x * 256 + threadIdx.x;
  if (v < n) dinv[v] = rsqrtf((float)(degi[v] + 1));  // +1 self-loop; deg>=1
}

// ---------- GEMM: C[n][NCOL] = A[n][128] @ W[128][NCOL] ----------
template<int NCOL>
__global__ __launch_bounds__(256) void gemm_kernel(const float* __restrict__ A,
    const float* __restrict__ W, float* __restrict__ C, int n) {
  __shared__ float sW[128 * NCOL];
  __shared__ float sA[32 * 128];
  const int tid = threadIdx.x;
  for (int i = tid * 4; i < 128 * NCOL; i += 256 * 4)
    *(float4*)&sW[i] = *(const float4*)&W[i];
  const int row0 = blockIdx.x * 32;
  #pragma unroll
  for (int j = 0; j < 4; ++j) {
    int fi = (tid + 256 * j) * 4;
    int r = fi >> 7, k = fi & 127;
    int row = row0 + r;
    float4 v = make_float4(0.f, 0.f, 0.f, 0.f);
    if (row < n) v = *(const float4*)&A[(size_t)row * 128 + k];
    *(float4*)&sA[r * 128 + k] = v;
  }
  __syncthreads();
  const int ty = tid >> 5;       // 0..7 -> rows ty*4 .. ty*4+3
  const int tx = tid & 31;       // cols tx + 32*c  (conflict-free sW reads)
  constexpr int CN = NCOL / 32;
  float acc[4][CN];
  #pragma unroll
  for (int r = 0; r < 4; ++r)
    #pragma unroll
    for (int c = 0; c < CN; ++c) acc[r][c] = 0.f;
  for (int k = 0; k < 128; k += 4) {
    float4 a[4];
    #pragma unroll
    for (int r = 0; r < 4; ++r) a[r] = *(const float4*)&sA[(ty * 4 + r) * 128 + k];
    #pragma unroll
    for (int kk = 0; kk < 4; ++kk) {
      #pragma unroll
      for (int c = 0; c < CN; ++c) {
        float wv = sW[(k + kk) * NCOL + tx + 32 * c];
        #pragma unroll
        for (int r = 0; r < 4; ++r)
          acc[r][c] = fmaf(((const float*)&a[r])[kk], wv, acc[r][c]);
      }
    }
  }
  #pragma unroll
  for (int r = 0; r < 4; ++r) {
    int row = row0 + ty * 4 + r;
    if (row < n) {
      #pragma unroll
      for (int c = 0; c < CN; ++c)
        C[(size_t)row * NCOL + tx + 32 * c] = acc[r][c];
    }
  }
}

// ---------- z = b + dinv^2 * y  (zero+bias+self-loop fused) ----------
template<int NCOL>
__global__ void initz_kernel(const float* __restrict__ y, const float* __restrict__ dinv,
    const float* __restrict__ b, float* __restrict__ z, int n) {
  int t = blockIdx.x * 256 + threadIdx.x;
  int total = n * (NCOL / 4);
  if (t >= total) return;
  int v = t / (NCOL / 4);
  int g = t % (NCOL / 4);
  float di = dinv[v];
  float co = di * di;
  float4 yv = *(const float4*)&y[(size_t)t * 4];
  float4 bv = *(const float4*)&b[g * 4];
  float4 o;
  o.x = bv.x + co * yv.x; o.y = bv.y + co * yv.y;
  o.z = bv.z + co * yv.z; o.w = bv.w + co * yv.w;
  *(float4*)&z[(size_t)t * 4] = o;
}

// ---------- edge scatter: z[dst] += y[src] * dinv[src]*dinv[dst] ----------
template<int NCOL>
__global__ __launch_bounds__(256) void scatter_kernel(const int* __restrict__ src,
    const int* __restrict__ dst, const float* __restrict__ dinv,
    const float* __restrict__ y, float* __restrict__ z, int E) {
  constexpr int TPE = NCOL / 4;  // threads per edge (float4 each)
  int t = blockIdx.x * 256 + threadIdx.x;
  if (t >= E * TPE) return;
  int e = t / TPE;
  int g = t % TPE;
  int s = src[e], d = dst[e];
  float coeff = dinv[s] * dinv[d];
  float4 v = *(const float4*)&y[(size_t)s * NCOL + g * 4];
  float* zp = &z[(size_t)d * NCOL + g * 4];
  atomicAdd(zp + 0, v.x * coeff);
  atomicAdd(zp + 1, v.y * coeff);
  atomicAdd(zp + 2, v.z * coeff);
  atomicAdd(zp + 3, v.w * coeff);
}

// ---------- batchnorm stats: deterministic two-pass ----------
__global__ __launch_bounds__(256) void stats_kernel(const float* __restrict__ z,
    float* __restrict__ psum, float* __restrict__ psq, int n) {
  const int tid = threadIdx.x;
  const int total = n * 128;
  float s = 0.f, s2 = 0.f;
  for (int i = blockIdx.x * 256 + tid; i < total; i += gridDim.x * 256) {
    float v = z[i];                 // stride multiple of 128 -> fixed channel tid%128
    s += v; s2 += v * v;
  }
  __shared__ float red[256];
  red[tid] = s; __syncthreads();
  if (tid < 128) psum[blockIdx.x * 128 + tid] = red[tid] + red[tid + 128];
  __syncthreads();
  red[tid] = s2; __syncthreads();
  if (tid < 128) psq[blockIdx.x * 128 + tid] = red[tid] + red[tid + 128];
}

__global__ void bnfin_kernel(const float* __restrict__ psum, const float* __restrict__ psq,
    const float* __restrict__ gamma, const float* __restrict__ beta,
    float* __restrict__ scale, float* __restrict__ shift, int n, int nb) {
  int c = threadIdx.x;  // 128 threads
  float s = 0.f, s2 = 0.f;
  for (int b = 0; b < nb; ++b) { s += psum[b * 128 + c]; s2 += psq[b * 128 + c]; }
  float mean = s / (float)n;
  float var = s2 / (float)n - mean * mean;
  float inv = rsqrtf(var + EPS);
  float sc = gamma[c] * inv;
  scale[c] = sc;
  shift[c] = beta[c] - mean * sc;
}

// ---------- x_out = leaky(z*scale+shift) + x_res ----------
__global__ void bnapply_kernel(const float* __restrict__ z, const float* __restrict__ scale,
    const float* __restrict__ shift, const float* __restrict__ xres,
    float* __restrict__ xout, int n) {
  int t = blockIdx.x * 256 + threadIdx.x;
  int total = n * 32;
  if (t >= total) return;
  int g = t & 31;
  float4 zv = *(const float4*)&z[(size_t)t * 4];
  float4 sc = *(const float4*)&scale[g * 4];
  float4 sh = *(const float4*)&shift[g * 4];
  float4 xr = *(const float4*)&xres[(size_t)t * 4];
  float4 o; float u;
  u = fmaf(zv.x, sc.x, sh.x); o.x = (u >= 0.f ? u : SLOPE * u) + xr.x;
  u = fmaf(zv.y, sc.y, sh.y); o.y = (u >= 0.f ? u : SLOPE * u) + xr.y;
  u = fmaf(zv.z, sc.z, sh.z); o.z = (u >= 0.f ? u : SLOPE * u) + xr.z;
  u = fmaf(zv.w, sc.w, sh.w); o.w = (u >= 0.f ? u : SLOPE * u) + xr.w;
  *(float4*)&xout[(size_t)t * 4] = o;
}

extern "C" void kernel_launch(void* const* d_in, const int* in_sizes, int n_in,
                              void* d_out, int out_size, void* d_ws, size_t ws_size,
                              hipStream_t stream) {
  const float* x     = (const float*)d_in[0];
  const int*   ei    = (const int*)d_in[1];
  const float* Ws    = (const float*)d_in[2];
  const float* bs    = (const float*)d_in[3];
  const float* Wmu   = (const float*)d_in[4];
  const float* bmu   = (const float*)d_in[5];
  const float* Wlv   = (const float*)d_in[6];
  const float* blv   = (const float*)d_in[7];
  const float* gamma = (const float*)d_in[8];
  const float* beta  = (const float*)d_in[9];
  float* out = (float*)d_out;

  const int n = in_sizes[0] / 128;
  const int E = in_sizes[1] / 2;
  const int* srcI = ei;        // edge_index[0]
  const int* dstI = ei + E;    // edge_index[1]

  char* wsp = (char*)d_ws;
  size_t off = 0;
  auto alloc = [&](size_t bytes) -> void* {
    void* p = wsp + off;
    off += (bytes + 255) & ~(size_t)255;
    return p;
  };
  int*   degi  = (int*)alloc((size_t)n * 4);
  float* dinv  = (float*)alloc((size_t)n * 4);
  float* xbuf  = (float*)alloc((size_t)n * 128 * 4);
  float* y     = (float*)alloc((size_t)n * 128 * 4);
  float* z     = (float*)alloc((size_t)n * 128 * 4);
  float* psum  = (float*)alloc((size_t)STAT_BLOCKS * 128 * 4);
  float* psq   = (float*)alloc((size_t)STAT_BLOCKS * 128 * 4);
  float* scale = (float*)alloc(128 * 4);
  float* shift = (float*)alloc(128 * 4);
  (void)n_in; (void)out_size; (void)ws_size;

  hipMemsetAsync(degi, 0, (size_t)n * 4, stream);
  deg_kernel<<<cdiv(E, 256), 256, 0, stream>>>(dstI, degi, E);
  dinv_kernel<<<cdiv(n, 256), 256, 0, stream>>>(degi, dinv, n);

  const float* xcur = x;
  for (int l = 0; l < 3; ++l) {
    gemm_kernel<128><<<cdiv(n, 32), 256, 0, stream>>>(xcur, Ws + (size_t)l * 128 * 128, y, n);
    initz_kernel<128><<<cdiv((long)n * 32, 256), 256, 0, stream>>>(y, dinv, bs + l * 128, z, n);
    scatter_kernel<128><<<cdiv((long)E * 32, 256), 256, 0, stream>>>(srcI, dstI, dinv, y, z, E);
    stats_kernel<<<STAT_BLOCKS, 256, 0, stream>>>(z, psum, psq, n);
    bnfin_kernel<<<1, 128, 0, stream>>>(psum, psq, gamma, beta, scale, shift, n, STAT_BLOCKS);
    bnapply_kernel<<<cdiv((long)n * 32, 256), 256, 0, stream>>>(z, scale, shift, xcur, xbuf, n);
    xcur = xbuf;
  }

  // mu head
  gemm_kernel<64><<<cdiv(n, 32), 256, 0, stream>>>(xcur, Wmu, y, n);
  initz_kernel<64><<<cdiv((long)n * 16, 256), 256, 0, stream>>>(y, dinv, bmu, out, n);
  scatter_kernel<64><<<cdiv((long)E * 16, 256), 256, 0, stream>>>(srcI, dstI, dinv, y, out, E);
  // logvar head
  gemm_kernel<64><<<cdiv(n, 32), 256, 0, stream>>>(xcur, Wlv, y, n);
  initz_kernel<64><<<cdiv((long)n * 16, 256), 256, 0, stream>>>(y, dinv, blv, out + (size_t)n * 64, n);
  scatter_kernel<64><<<cdiv((long)E * 16, 256), 256, 0, stream>>>(srcI, dstI, dinv, y, out + (size_t)n * 64, E);
}

// Round 2
// 945.206 us; speedup vs baseline: 5.0466x; 5.0466x over previous
//
#include <hip/hip_runtime.h>

#define EPS 1e-5f
#define SLOPE 0.01f
#define STAT_BLOCKS 240

static inline int cdiv(long a, int b) { return (int)((a + b - 1) / b); }

// ---------- degree ----------
__global__ void deg_kernel(const int* __restrict__ dst, int* __restrict__ degi, int E) {
  int e = blockIdx.x * 256 + threadIdx.x;
  if (e < E) atomicAdd(&degi[dst[e]], 1);
}

__global__ void dinv_kernel(const int* __restrict__ degi, float* __restrict__ dinv, int n) {
  int v = blockIdx.x * 256 + threadIdx.x;
  if (v < n) dinv[v] = rsqrtf((float)(degi[v] + 1));  // +1 self-loop
}

// ---------- exclusive scan (single block, 1024 thr, shfl waves) ----------
__global__ __launch_bounds__(1024) void scan_kernel(const int* __restrict__ degi,
    int* __restrict__ ptr, int n) {
  const int tid = threadIdx.x;
  const int lane = tid & 63, wv = tid >> 6;
  __shared__ int wsum[16];
  __shared__ int carry_s;
  if (tid == 0) carry_s = 0;
  __syncthreads();
  int nchunk = (n + 1023) >> 10;
  for (int ch = 0; ch < nchunk; ++ch) {
    int i = (ch << 10) + tid;
    int v = (i < n) ? degi[i] : 0;
    int inc = v;
    #pragma unroll
    for (int ofs = 1; ofs < 64; ofs <<= 1) {
      int t = __shfl_up(inc, ofs, 64);
      if (lane >= ofs) inc += t;
    }
    if (lane == 63) wsum[wv] = inc;
    __syncthreads();                      // wsum raw
    if (tid < 16) {
      int t = wsum[tid];
      #pragma unroll
      for (int ofs = 1; ofs < 16; ofs <<= 1) {
        int u = __shfl_up(t, ofs, 64);
        if (tid >= ofs) t += u;
      }
      wsum[tid] = t;                      // inclusive over waves
    }
    __syncthreads();                      // wsum scanned
    int waveoff = wv ? wsum[wv - 1] : 0;
    int carry = carry_s;
    if (i < n) ptr[i] = carry + waveoff + inc - v;   // exclusive
    __syncthreads();                      // all read carry_s
    if (tid == 0) carry_s = carry + wsum[15];
    __syncthreads();                      // carry updated
  }
  if (tid == 0) ptr[n] = carry_s;
}

// ---------- CSR fill: csr[pos] = {src, dinv[src]*dinv[dst]} grouped by dst ----------
__global__ void fill_kernel(const int* __restrict__ src, const int* __restrict__ dst,
    const float* __restrict__ dinv, const int* __restrict__ ptr,
    int* __restrict__ fillc, int2* __restrict__ csr, int E) {
  int e = blockIdx.x * 256 + threadIdx.x;
  if (e >= E) return;
  int s = src[e], d = dst[e];
  int pos = ptr[d] + atomicAdd(&fillc[d], 1);
  float c = dinv[s] * dinv[d];
  csr[pos] = make_int2(s, __float_as_int(c));
}

// ---------- GEMM: C[n][NCOL] = A[n][128] @ W[128][NCOL] ----------
template<int NCOL>
__global__ __launch_bounds__(256) void gemm_kernel(const float* __restrict__ A,
    const float* __restrict__ W, float* __restrict__ C, int n) {
  __shared__ float sW[128 * NCOL];
  __shared__ float sA[32 * 128];
  const int tid = threadIdx.x;
  for (int i = tid * 4; i < 128 * NCOL; i += 256 * 4)
    *(float4*)&sW[i] = *(const float4*)&W[i];
  const int row0 = blockIdx.x * 32;
  #pragma unroll
  for (int j = 0; j < 4; ++j) {
    int fi = (tid + 256 * j) * 4;
    int r = fi >> 7, k = fi & 127;
    int row = row0 + r;
    float4 v = make_float4(0.f, 0.f, 0.f, 0.f);
    if (row < n) v = *(const float4*)&A[(size_t)row * 128 + k];
    *(float4*)&sA[r * 128 + k] = v;
  }
  __syncthreads();
  const int ty = tid >> 5;
  const int tx = tid & 31;
  constexpr int CN = NCOL / 32;
  float acc[4][CN];
  #pragma unroll
  for (int r = 0; r < 4; ++r)
    #pragma unroll
    for (int c = 0; c < CN; ++c) acc[r][c] = 0.f;
  for (int k = 0; k < 128; k += 4) {
    float4 a[4];
    #pragma unroll
    for (int r = 0; r < 4; ++r) a[r] = *(const float4*)&sA[(ty * 4 + r) * 128 + k];
    #pragma unroll
    for (int kk = 0; kk < 4; ++kk) {
      #pragma unroll
      for (int c = 0; c < CN; ++c) {
        float wv = sW[(k + kk) * NCOL + tx + 32 * c];
        #pragma unroll
        for (int r = 0; r < 4; ++r)
          acc[r][c] = fmaf(((const float*)&a[r])[kk], wv, acc[r][c]);
      }
    }
  }
  #pragma unroll
  for (int r = 0; r < 4; ++r) {
    int row = row0 + ty * 4 + r;
    if (row < n) {
      #pragma unroll
      for (int c = 0; c < CN; ++c)
        C[(size_t)row * NCOL + tx + 32 * c] = acc[r][c];
    }
  }
}

// ---------- gather propagate: z[v] = b + dinv[v]^2*y[v] + sum_in coeff*y[src] ----------
template<int NCOL>
__global__ __launch_bounds__(256) void gather_kernel(const int* __restrict__ ptr,
    const int2* __restrict__ csr, const float* __restrict__ y,
    const float* __restrict__ b, const float* __restrict__ dinv,
    float* __restrict__ z, int n) {
  constexpr int VPL = NCOL / 64;  // floats per lane
  int w = (blockIdx.x * 256 + threadIdx.x) >> 6;  // node = wave id
  int lane = threadIdx.x & 63;
  if (w >= n) return;
  int col = lane * VPL;
  float dv = dinv[w];
  float c0 = dv * dv;
  float acc[VPL];
  if constexpr (VPL == 2) {
    float2 yv = *(const float2*)&y[(size_t)w * NCOL + col];
    acc[0] = b[col]     + c0 * yv.x;
    acc[1] = b[col + 1] + c0 * yv.y;
  } else {
    acc[0] = b[col] + c0 * y[(size_t)w * NCOL + col];
  }
  int beg = ptr[w], end = ptr[w + 1];
  for (int j = beg; j < end; ++j) {
    int2 ed = csr[j];                 // uniform across wave -> broadcast
    int s = ed.x;
    float c = __int_as_float(ed.y);
    if constexpr (VPL == 2) {
      float2 yv = *(const float2*)&y[(size_t)s * NCOL + col];
      acc[0] = fmaf(c, yv.x, acc[0]);
      acc[1] = fmaf(c, yv.y, acc[1]);
    } else {
      acc[0] = fmaf(c, y[(size_t)s * NCOL + col], acc[0]);
    }
  }
  if constexpr (VPL == 2) {
    *(float2*)&z[(size_t)w * NCOL + col] = make_float2(acc[0], acc[1]);
  } else {
    z[(size_t)w * NCOL + col] = acc[0];
  }
}

// ---------- batchnorm stats: deterministic two-pass ----------
__global__ __launch_bounds__(256) void stats_kernel(const float* __restrict__ z,
    float* __restrict__ psum, float* __restrict__ psq, int n) {
  const int tid = threadIdx.x;
  const int total = n * 128;
  float s = 0.f, s2 = 0.f;
  for (int i = blockIdx.x * 256 + tid; i < total; i += gridDim.x * 256) {
    float v = z[i];
    s += v; s2 += v * v;
  }
  __shared__ float red[256];
  red[tid] = s; __syncthreads();
  if (tid < 128) psum[blockIdx.x * 128 + tid] = red[tid] + red[tid + 128];
  __syncthreads();
  red[tid] = s2; __syncthreads();
  if (tid < 128) psq[blockIdx.x * 128 + tid] = red[tid] + red[tid + 128];
}

__global__ void bnfin_kernel(const float* __restrict__ psum, const float* __restrict__ psq,
    const float* __restrict__ gamma, const float* __restrict__ beta,
    float* __restrict__ scale, float* __restrict__ shift, int n, int nb) {
  int c = threadIdx.x;  // 128 threads
  float s = 0.f, s2 = 0.f;
  for (int b = 0; b < nb; ++b) { s += psum[b * 128 + c]; s2 += psq[b * 128 + c]; }
  float mean = s / (float)n;
  float var = s2 / (float)n - mean * mean;
  float inv = rsqrtf(var + EPS);
  float sc = gamma[c] * inv;
  scale[c] = sc;
  shift[c] = beta[c] - mean * sc;
}

// ---------- x_out = leaky(z*scale+shift) + x_res ----------
__global__ void bnapply_kernel(const float* __restrict__ z, const float* __restrict__ scale,
    const float* __restrict__ shift, const float* __restrict__ xres,
    float* __restrict__ xout, int n) {
  int t = blockIdx.x * 256 + threadIdx.x;
  int total = n * 32;
  if (t >= total) return;
  int g = t & 31;
  float4 zv = *(const float4*)&z[(size_t)t * 4];
  float4 sc = *(const float4*)&scale[g * 4];
  float4 sh = *(const float4*)&shift[g * 4];
  float4 xr = *(const float4*)&xres[(size_t)t * 4];
  float4 o; float u;
  u = fmaf(zv.x, sc.x, sh.x); o.x = (u >= 0.f ? u : SLOPE * u) + xr.x;
  u = fmaf(zv.y, sc.y, sh.y); o.y = (u >= 0.f ? u : SLOPE * u) + xr.y;
  u = fmaf(zv.z, sc.z, sh.z); o.z = (u >= 0.f ? u : SLOPE * u) + xr.z;
  u = fmaf(zv.w, sc.w, sh.w); o.w = (u >= 0.f ? u : SLOPE * u) + xr.w;
  *(float4*)&xout[(size_t)t * 4] = o;
}

extern "C" void kernel_launch(void* const* d_in, const int* in_sizes, int n_in,
                              void* d_out, int out_size, void* d_ws, size_t ws_size,
                              hipStream_t stream) {
  const float* x     = (const float*)d_in[0];
  const int*   ei    = (const int*)d_in[1];
  const float* Ws    = (const float*)d_in[2];
  const float* bs    = (const float*)d_in[3];
  const float* Wmu   = (const float*)d_in[4];
  const float* bmu   = (const float*)d_in[5];
  const float* Wlv   = (const float*)d_in[6];
  const float* blv   = (const float*)d_in[7];
  const float* gamma = (const float*)d_in[8];
  const float* beta  = (const float*)d_in[9];
  float* out = (float*)d_out;

  const int n = in_sizes[0] / 128;
  const int E = in_sizes[1] / 2;
  const int* srcI = ei;
  const int* dstI = ei + E;

  char* wsp = (char*)d_ws;
  size_t off = 0;
  auto alloc = [&](size_t bytes) -> void* {
    void* p = wsp + off;
    off += (bytes + 255) & ~(size_t)255;
    return p;
  };
  int*   degi  = (int*)alloc((size_t)n * 4);
  float* dinv  = (float*)alloc((size_t)n * 4);
  int*   ptr   = (int*)alloc((size_t)(n + 1) * 4);
  int*   fillc = (int*)alloc((size_t)n * 4);
  int2*  csr   = (int2*)alloc((size_t)E * 8);
  float* xbuf  = (float*)alloc((size_t)n * 128 * 4);
  float* y     = (float*)alloc((size_t)n * 128 * 4);
  float* z     = (float*)alloc((size_t)n * 128 * 4);
  float* psum  = (float*)alloc((size_t)STAT_BLOCKS * 128 * 4);
  float* psq   = (float*)alloc((size_t)STAT_BLOCKS * 128 * 4);
  float* scale = (float*)alloc(128 * 4);
  float* shift = (float*)alloc(128 * 4);
  (void)n_in; (void)out_size; (void)ws_size;

  hipMemsetAsync(degi, 0, (size_t)n * 4, stream);
  hipMemsetAsync(fillc, 0, (size_t)n * 4, stream);
  deg_kernel<<<cdiv(E, 256), 256, 0, stream>>>(dstI, degi, E);
  dinv_kernel<<<cdiv(n, 256), 256, 0, stream>>>(degi, dinv, n);
  scan_kernel<<<1, 1024, 0, stream>>>(degi, ptr, n);
  fill_kernel<<<cdiv(E, 256), 256, 0, stream>>>(srcI, dstI, dinv, ptr, fillc, csr, E);

  const float* xcur = x;
  for (int l = 0; l < 3; ++l) {
    gemm_kernel<128><<<cdiv(n, 32), 256, 0, stream>>>(xcur, Ws + (size_t)l * 128 * 128, y, n);
    gather_kernel<128><<<cdiv((long)n * 64, 256), 256, 0, stream>>>(ptr, csr, y, bs + l * 128, dinv, z, n);
    stats_kernel<<<STAT_BLOCKS, 256, 0, stream>>>(z, psum, psq, n);
    bnfin_kernel<<<1, 128, 0, stream>>>(psum, psq, gamma, beta, scale, shift, n, STAT_BLOCKS);
    bnapply_kernel<<<cdiv((long)n * 32, 256), 256, 0, stream>>>(z, scale, shift, xcur, xbuf, n);
    xcur = xbuf;
  }

  // mu head
  gemm_kernel<64><<<cdiv(n, 32), 256, 0, stream>>>(xcur, Wmu, y, n);
  gather_kernel<64><<<cdiv((long)n * 64, 256), 256, 0, stream>>>(ptr, csr, y, bmu, dinv, out, n);
  // logvar head
  gemm_kernel<64><<<cdiv(n, 32), 256, 0, stream>>>(xcur, Wlv, y, n);
  gather_kernel<64><<<cdiv((long)n * 64, 256), 256, 0, stream>>>(ptr, csr, y, blv, dinv, out + (size_t)n * 64, n);
}

// Round 3
// 717.628 us; speedup vs baseline: 6.6470x; 1.3171x over previous
//
#include <hip/hip_runtime.h>

typedef unsigned int uint;
typedef unsigned short ushort;

#define EPS 1e-5f
#define SLOPE 0.01f
#define STAT_BLOCKS 240

static inline int cdiv(long a, int b) { return (int)((a + b - 1) / b); }

__device__ inline float bf_lo(uint v) { return __uint_as_float(v << 16); }
__device__ inline float bf_hi(uint v) { return __uint_as_float(v & 0xffff0000u); }
__device__ inline ushort f2bf(float f) {
  uint u = __float_as_uint(f);
  u += 0x7fffu + ((u >> 16) & 1u);   // RNE
  return (ushort)(u >> 16);
}

// ---------- degree ----------
__global__ void deg_kernel(const int* __restrict__ dst, int* __restrict__ degi, int E) {
  int e = blockIdx.x * 256 + threadIdx.x;
  if (e < E) atomicAdd(&degi[dst[e]], 1);
}

__global__ void dinv_kernel(const int* __restrict__ degi, float* __restrict__ dinv, int n) {
  int v = blockIdx.x * 256 + threadIdx.x;
  if (v < n) dinv[v] = rsqrtf((float)(degi[v] + 1));  // +1 self-loop
}

// ---------- parallel exclusive scan: block sums -> scan sums -> write ----------
__global__ __launch_bounds__(256) void bsum_kernel(const int* __restrict__ degi,
    int* __restrict__ bsum, int n) {
  int tid = threadIdx.x;
  int i = blockIdx.x * 256 + tid;
  int v = (i < n) ? degi[i] : 0;
  #pragma unroll
  for (int ofs = 32; ofs; ofs >>= 1) v += __shfl_down(v, ofs, 64);
  __shared__ int ws[4];
  if ((tid & 63) == 0) ws[tid >> 6] = v;
  __syncthreads();
  if (tid == 0) bsum[blockIdx.x] = ws[0] + ws[1] + ws[2] + ws[3];
}

__global__ __launch_bounds__(256) void bscan_kernel(const int* __restrict__ bsum,
    int* __restrict__ bofs, int* __restrict__ ptr_end, int nb) {
  int tid = threadIdx.x, lane = tid & 63, wv = tid >> 6;
  __shared__ int wsum[4];
  __shared__ int carry_s, tot_s;
  if (tid == 0) carry_s = 0;
  __syncthreads();
  for (int base = 0; base < nb; base += 256) {
    int i = base + tid;
    int v = (i < nb) ? bsum[i] : 0;
    int inc = v;
    #pragma unroll
    for (int ofs = 1; ofs < 64; ofs <<= 1) {
      int t = __shfl_up(inc, ofs, 64);
      if (lane >= ofs) inc += t;
    }
    if (lane == 63) wsum[wv] = inc;
    __syncthreads();
    if (tid == 0) {
      int a = carry_s;
      for (int w = 0; w < 4; ++w) { int t = wsum[w]; wsum[w] = a; a += t; }
      tot_s = a;
    }
    __syncthreads();
    if (i < nb) bofs[i] = wsum[wv] + inc - v;
    __syncthreads();
    if (tid == 0) carry_s = tot_s;
    __syncthreads();
  }
  if (tid == 0) *ptr_end = carry_s;
}

__global__ __launch_bounds__(256) void ptr_kernel(const int* __restrict__ degi,
    const int* __restrict__ bofs, int* __restrict__ ptr, int n) {
  int tid = threadIdx.x, lane = tid & 63, wv = tid >> 6;
  int i = blockIdx.x * 256 + tid;
  int v = (i < n) ? degi[i] : 0;
  int inc = v;
  #pragma unroll
  for (int ofs = 1; ofs < 64; ofs <<= 1) {
    int t = __shfl_up(inc, ofs, 64);
    if (lane >= ofs) inc += t;
  }
  __shared__ int wsum[4], woff[4];
  if (lane == 63) wsum[wv] = inc;
  __syncthreads();
  if (tid == 0) {
    int a = 0;
    for (int w = 0; w < 4; ++w) { woff[w] = a; a += wsum[w]; }
  }
  __syncthreads();
  if (i < n) ptr[i] = bofs[blockIdx.x] + woff[wv] + inc - v;
}

// ---------- CSR fill ----------
__global__ void fill_kernel(const int* __restrict__ src, const int* __restrict__ dst,
    const float* __restrict__ dinv, const int* __restrict__ ptr,
    int* __restrict__ fillc, int2* __restrict__ csr, int E) {
  int e = blockIdx.x * 256 + threadIdx.x;
  if (e >= E) return;
  int s = src[e], d = dst[e];
  int pos = ptr[d] + atomicAdd(&fillc[d], 1);
  float c = dinv[s] * dinv[d];
  csr[pos] = make_int2(s, __float_as_int(c));
}

// ---------- GEMM (optionally fused BN-apply/leaky/residual staging), bf16 out ----------
template<bool FUSED, bool WRITEX, bool TWOW>
__global__ __launch_bounds__(256) void gemm_kernel(
    const float* __restrict__ A,           // plain input or z (if FUSED)
    const float* __restrict__ scale, const float* __restrict__ shift,
    const float* __restrict__ xres, float* __restrict__ xout,
    const float* __restrict__ W0, const float* __restrict__ W1,
    ushort* __restrict__ Cbf, int n) {
  __shared__ float sW[128 * 128];
  __shared__ float sA[32 * 128];
  const int tid = threadIdx.x;
  for (int i = tid * 4; i < 128 * 128; i += 256 * 4) {
    float4 wv;
    if (TWOW) {
      int k = i >> 7, c = i & 127;
      wv = (c < 64) ? *(const float4*)&W0[k * 64 + c]
                    : *(const float4*)&W1[k * 64 + (c - 64)];
    } else {
      wv = *(const float4*)&W0[i];
    }
    *(float4*)&sW[i] = wv;
  }
  const int row0 = blockIdx.x * 32;
  #pragma unroll
  for (int j = 0; j < 4; ++j) {
    int fi = (tid + 256 * j) * 4;
    int r = fi >> 7, k = fi & 127;
    int row = row0 + r;
    float4 a = make_float4(0.f, 0.f, 0.f, 0.f);
    if (row < n) {
      if (FUSED) {
        float4 zv = *(const float4*)&A[(size_t)row * 128 + k];
        float4 xr = *(const float4*)&xres[(size_t)row * 128 + k];
        float4 sc = *(const float4*)&scale[k];
        float4 sh = *(const float4*)&shift[k];
        float u;
        u = fmaf(zv.x, sc.x, sh.x); u = u >= 0.f ? u : SLOPE * u; a.x = u + xr.x;
        u = fmaf(zv.y, sc.y, sh.y); u = u >= 0.f ? u : SLOPE * u; a.y = u + xr.y;
        u = fmaf(zv.z, sc.z, sh.z); u = u >= 0.f ? u : SLOPE * u; a.z = u + xr.z;
        u = fmaf(zv.w, sc.w, sh.w); u = u >= 0.f ? u : SLOPE * u; a.w = u + xr.w;
        if (WRITEX) *(float4*)&xout[(size_t)row * 128 + k] = a;
      } else {
        a = *(const float4*)&A[(size_t)row * 128 + k];
      }
    }
    *(float4*)&sA[r * 128 + k] = a;
  }
  __syncthreads();
  const int ty = tid >> 5;
  const int tx = tid & 31;
  float acc[4][4];
  #pragma unroll
  for (int r = 0; r < 4; ++r)
    #pragma unroll
    for (int c = 0; c < 4; ++c) acc[r][c] = 0.f;
  for (int k = 0; k < 128; k += 4) {
    float4 a[4];
    #pragma unroll
    for (int r = 0; r < 4; ++r) a[r] = *(const float4*)&sA[(ty * 4 + r) * 128 + k];
    #pragma unroll
    for (int kk = 0; kk < 4; ++kk) {
      #pragma unroll
      for (int c = 0; c < 4; ++c) {
        float wv = sW[(k + kk) * 128 + tx + 32 * c];
        #pragma unroll
        for (int r = 0; r < 4; ++r)
          acc[r][c] = fmaf(((const float*)&a[r])[kk], wv, acc[r][c]);
      }
    }
  }
  #pragma unroll
  for (int r = 0; r < 4; ++r) {
    int row = row0 + ty * 4 + r;
    if (row < n) {
      #pragma unroll
      for (int c = 0; c < 4; ++c)
        Cbf[(size_t)row * 128 + tx + 32 * c] = f2bf(acc[r][c]);
    }
  }
}

// ---------- gather propagate (bf16 y), wave per node, lane = 2 channels ----------
__global__ __launch_bounds__(256) void gather_layer(const int* __restrict__ ptr,
    const int2* __restrict__ csr, const uint* __restrict__ ybf,
    const float* __restrict__ b, const float* __restrict__ dinv,
    float* __restrict__ z, int n) {
  int w = (blockIdx.x * 256 + threadIdx.x) >> 6;
  if (w >= n) return;
  int lane = threadIdx.x & 63;
  float dv = dinv[w], c0 = dv * dv;
  uint yv = ybf[(size_t)w * 64 + lane];
  float2 bb = *(const float2*)&b[lane * 2];
  float2 acc;
  acc.x = fmaf(c0, bf_lo(yv), bb.x);
  acc.y = fmaf(c0, bf_hi(yv), bb.y);
  int j = ptr[w], end = ptr[w + 1];
  for (; j + 1 < end; j += 2) {
    int2 e0 = csr[j], e1 = csr[j + 1];
    uint v0 = ybf[(size_t)e0.x * 64 + lane];
    uint v1 = ybf[(size_t)e1.x * 64 + lane];
    float cf0 = __int_as_float(e0.y), cf1 = __int_as_float(e1.y);
    acc.x = fmaf(cf0, bf_lo(v0), acc.x); acc.y = fmaf(cf0, bf_hi(v0), acc.y);
    acc.x = fmaf(cf1, bf_lo(v1), acc.x); acc.y = fmaf(cf1, bf_hi(v1), acc.y);
  }
  if (j < end) {
    int2 e0 = csr[j];
    uint v0 = ybf[(size_t)e0.x * 64 + lane];
    float cf = __int_as_float(e0.y);
    acc.x = fmaf(cf, bf_lo(v0), acc.x); acc.y = fmaf(cf, bf_hi(v0), acc.y);
  }
  *(float2*)&z[(size_t)w * 128 + lane * 2] = acc;
}

// ---------- heads gather: cols 0-63 -> mu, 64-127 -> logvar ----------
__global__ __launch_bounds__(256) void gather_heads(const int* __restrict__ ptr,
    const int2* __restrict__ csr, const uint* __restrict__ ybf,
    const float* __restrict__ bmu, const float* __restrict__ blv,
    const float* __restrict__ dinv, float* __restrict__ out, int n) {
  int w = (blockIdx.x * 256 + threadIdx.x) >> 6;
  if (w >= n) return;
  int lane = threadIdx.x & 63;
  int col = lane * 2;
  float* obase; const float* bias; int cc;
  if (col < 64) { obase = out; bias = bmu; cc = col; }
  else { obase = out + (size_t)n * 64; bias = blv; cc = col - 64; }
  float dv = dinv[w], c0 = dv * dv;
  uint yv = ybf[(size_t)w * 64 + lane];
  float2 acc;
  acc.x = fmaf(c0, bf_lo(yv), bias[cc]);
  acc.y = fmaf(c0, bf_hi(yv), bias[cc + 1]);
  int j = ptr[w], end = ptr[w + 1];
  for (; j + 1 < end; j += 2) {
    int2 e0 = csr[j], e1 = csr[j + 1];
    uint v0 = ybf[(size_t)e0.x * 64 + lane];
    uint v1 = ybf[(size_t)e1.x * 64 + lane];
    float cf0 = __int_as_float(e0.y), cf1 = __int_as_float(e1.y);
    acc.x = fmaf(cf0, bf_lo(v0), acc.x); acc.y = fmaf(cf0, bf_hi(v0), acc.y);
    acc.x = fmaf(cf1, bf_lo(v1), acc.x); acc.y = fmaf(cf1, bf_hi(v1), acc.y);
  }
  if (j < end) {
    int2 e0 = csr[j];
    uint v0 = ybf[(size_t)e0.x * 64 + lane];
    float cf = __int_as_float(e0.y);
    acc.x = fmaf(cf, bf_lo(v0), acc.x); acc.y = fmaf(cf, bf_hi(v0), acc.y);
  }
  *(float2*)&obase[(size_t)w * 64 + cc] = acc;
}

// ---------- batchnorm stats: deterministic two-pass ----------
__global__ __launch_bounds__(256) void stats_kernel(const float* __restrict__ z,
    float* __restrict__ psum, float* __restrict__ psq, int n) {
  const int tid = threadIdx.x;
  const int total = n * 128;
  float s = 0.f, s2 = 0.f;
  for (int i = blockIdx.x * 256 + tid; i < total; i += gridDim.x * 256) {
    float v = z[i];
    s += v; s2 += v * v;
  }
  __shared__ float red[256];
  red[tid] = s; __syncthreads();
  if (tid < 128) psum[blockIdx.x * 128 + tid] = red[tid] + red[tid + 128];
  __syncthreads();
  red[tid] = s2; __syncthreads();
  if (tid < 128) psq[blockIdx.x * 128 + tid] = red[tid] + red[tid + 128];
}

__global__ void bnfin_kernel(const float* __restrict__ psum, const float* __restrict__ psq,
    const float* __restrict__ gamma, const float* __restrict__ beta,
    float* __restrict__ scale, float* __restrict__ shift, int n, int nb) {
  int c = threadIdx.x;  // 128 threads
  float s = 0.f, s2 = 0.f;
  for (int b = 0; b < nb; ++b) { s += psum[b * 128 + c]; s2 += psq[b * 128 + c]; }
  float mean = s / (float)n;
  float var = s2 / (float)n - mean * mean;
  float inv = rsqrtf(var + EPS);
  float sc = gamma[c] * inv;
  scale[c] = sc;
  shift[c] = beta[c] - mean * sc;
}

extern "C" void kernel_launch(void* const* d_in, const int* in_sizes, int n_in,
                              void* d_out, int out_size, void* d_ws, size_t ws_size,
                              hipStream_t stream) {
  const float* x     = (const float*)d_in[0];
  const int*   ei    = (const int*)d_in[1];
  const float* Ws    = (const float*)d_in[2];
  const float* bs    = (const float*)d_in[3];
  const float* Wmu   = (const float*)d_in[4];
  const float* bmu   = (const float*)d_in[5];
  const float* Wlv   = (const float*)d_in[6];
  const float* blv   = (const float*)d_in[7];
  const float* gamma = (const float*)d_in[8];
  const float* beta  = (const float*)d_in[9];
  float* out = (float*)d_out;

  const int n = in_sizes[0] / 128;
  const int E = in_sizes[1] / 2;
  const int* srcI = ei;
  const int* dstI = ei + E;
  const int nb = cdiv(n, 256);

  char* wsp = (char*)d_ws;
  size_t off = 0;
  auto alloc = [&](size_t bytes) -> void* {
    void* p = wsp + off;
    off += (bytes + 255) & ~(size_t)255;
    return p;
  };
  int*    degi  = (int*)alloc((size_t)n * 4);
  float*  dinv  = (float*)alloc((size_t)n * 4);
  int*    ptr   = (int*)alloc((size_t)(n + 1) * 4);
  int*    fillc = (int*)alloc((size_t)n * 4);
  int*    bsum  = (int*)alloc((size_t)nb * 4);
  int*    bofs  = (int*)alloc((size_t)nb * 4);
  int2*   csr   = (int2*)alloc((size_t)E * 8);
  ushort* ybf   = (ushort*)alloc((size_t)n * 128 * 2);
  float*  z     = (float*)alloc((size_t)n * 128 * 4);
  float*  xbuf  = (float*)alloc((size_t)n * 128 * 4);
  float*  psum  = (float*)alloc((size_t)STAT_BLOCKS * 128 * 4);
  float*  psq   = (float*)alloc((size_t)STAT_BLOCKS * 128 * 4);
  float*  scale = (float*)alloc(128 * 4);
  float*  shift = (float*)alloc(128 * 4);
  (void)n_in; (void)out_size; (void)ws_size;

  hipMemsetAsync(degi, 0, (size_t)n * 4, stream);
  hipMemsetAsync(fillc, 0, (size_t)n * 4, stream);
  deg_kernel<<<cdiv(E, 256), 256, 0, stream>>>(dstI, degi, E);
  dinv_kernel<<<cdiv(n, 256), 256, 0, stream>>>(degi, dinv, n);
  bsum_kernel<<<nb, 256, 0, stream>>>(degi, bsum, n);
  bscan_kernel<<<1, 256, 0, stream>>>(bsum, bofs, ptr + n, nb);
  ptr_kernel<<<nb, 256, 0, stream>>>(degi, bofs, ptr, n);
  fill_kernel<<<cdiv(E, 256), 256, 0, stream>>>(srcI, dstI, dinv, ptr, fillc, csr, E);

  const int ggrid = cdiv(n, 32);
  const int wgrid = cdiv((long)n * 64, 256);

  // layer 0
  gemm_kernel<false, false, false><<<ggrid, 256, 0, stream>>>(
      x, nullptr, nullptr, nullptr, nullptr, Ws, nullptr, ybf, n);
  gather_layer<<<wgrid, 256, 0, stream>>>(ptr, csr, (const uint*)ybf, bs, dinv, z, n);
  stats_kernel<<<STAT_BLOCKS, 256, 0, stream>>>(z, psum, psq, n);
  bnfin_kernel<<<1, 128, 0, stream>>>(psum, psq, gamma, beta, scale, shift, n, STAT_BLOCKS);
  // layer 1 (staging applies BN+leaky+res with xres=x, writes xbuf)
  gemm_kernel<true, true, false><<<ggrid, 256, 0, stream>>>(
      z, scale, shift, x, xbuf, Ws + 16384, nullptr, ybf, n);
  gather_layer<<<wgrid, 256, 0, stream>>>(ptr, csr, (const uint*)ybf, bs + 128, dinv, z, n);
  stats_kernel<<<STAT_BLOCKS, 256, 0, stream>>>(z, psum, psq, n);
  bnfin_kernel<<<1, 128, 0, stream>>>(psum, psq, gamma, beta, scale, shift, n, STAT_BLOCKS);
  // layer 2 (xres=xbuf, update xbuf in place; each block touches only its own rows)
  gemm_kernel<true, true, false><<<ggrid, 256, 0, stream>>>(
      z, scale, shift, xbuf, xbuf, Ws + 32768, nullptr, ybf, n);
  gather_layer<<<wgrid, 256, 0, stream>>>(ptr, csr, (const uint*)ybf, bs + 256, dinv, z, n);
  stats_kernel<<<STAT_BLOCKS, 256, 0, stream>>>(z, psum, psq, n);
  bnfin_kernel<<<1, 128, 0, stream>>>(psum, psq, gamma, beta, scale, shift, n, STAT_BLOCKS);
  // heads: one GEMM with W = [Wmu | Wlv], one gather writing both outputs
  gemm_kernel<true, false, true><<<ggrid, 256, 0, stream>>>(
      z, scale, shift, xbuf, nullptr, Wmu, Wlv, ybf, n);
  gather_heads<<<wgrid, 256, 0, stream>>>(ptr, csr, (const uint*)ybf, bmu, blv, dinv, out, n);
}

// Round 4
// 444.732 us; speedup vs baseline: 10.7257x; 1.6136x over previous
//
#include <hip/hip_runtime.h>

typedef unsigned int uint;
typedef unsigned short ushort;

#define EPS 1e-5f
#define SLOPE 0.01f
#define GATHER_BLOCKS 2048

static inline int cdiv(long a, int b) { return (int)((a + b - 1) / b); }

__device__ inline float bf_lo(uint v) { return __uint_as_float(v << 16); }
__device__ inline float bf_hi(uint v) { return __uint_as_float(v & 0xffff0000u); }
__device__ inline ushort f2bf(float f) {
  uint u = __float_as_uint(f);
  u += 0x7fffu + ((u >> 16) & 1u);   // RNE
  return (ushort)(u >> 16);
}

// ---------- degree ----------
__global__ void deg_kernel(const int* __restrict__ dst, int* __restrict__ degi, int E) {
  int e = blockIdx.x * 256 + threadIdx.x;
  if (e < E) atomicAdd(&degi[dst[e]], 1);
}

__global__ void dinv_kernel(const int* __restrict__ degi, float* __restrict__ dinv, int n) {
  int v = blockIdx.x * 256 + threadIdx.x;
  if (v < n) dinv[v] = rsqrtf((float)(degi[v] + 1));  // +1 self-loop
}

// ---------- parallel exclusive scan: block sums -> scan sums -> write ----------
__global__ __launch_bounds__(256) void bsum_kernel(const int* __restrict__ degi,
    int* __restrict__ bsum, int n) {
  int tid = threadIdx.x;
  int i = blockIdx.x * 256 + tid;
  int v = (i < n) ? degi[i] : 0;
  #pragma unroll
  for (int ofs = 32; ofs; ofs >>= 1) v += __shfl_down(v, ofs, 64);
  __shared__ int ws[4];
  if ((tid & 63) == 0) ws[tid >> 6] = v;
  __syncthreads();
  if (tid == 0) bsum[blockIdx.x] = ws[0] + ws[1] + ws[2] + ws[3];
}

__global__ __launch_bounds__(256) void bscan_kernel(const int* __restrict__ bsum,
    int* __restrict__ bofs, int* __restrict__ ptr_end, int nb) {
  int tid = threadIdx.x, lane = tid & 63, wv = tid >> 6;
  __shared__ int wsum[4];
  __shared__ int carry_s, tot_s;
  if (tid == 0) carry_s = 0;
  __syncthreads();
  for (int base = 0; base < nb; base += 256) {
    int i = base + tid;
    int v = (i < nb) ? bsum[i] : 0;
    int inc = v;
    #pragma unroll
    for (int ofs = 1; ofs < 64; ofs <<= 1) {
      int t = __shfl_up(inc, ofs, 64);
      if (lane >= ofs) inc += t;
    }
    if (lane == 63) wsum[wv] = inc;
    __syncthreads();
    if (tid == 0) {
      int a = carry_s;
      for (int w = 0; w < 4; ++w) { int t = wsum[w]; wsum[w] = a; a += t; }
      tot_s = a;
    }
    __syncthreads();
    if (i < nb) bofs[i] = wsum[wv] + inc - v;
    __syncthreads();
    if (tid == 0) carry_s = tot_s;
    __syncthreads();
  }
  if (tid == 0) *ptr_end = carry_s;
}

__global__ __launch_bounds__(256) void ptr_kernel(const int* __restrict__ degi,
    const int* __restrict__ bofs, int* __restrict__ ptr, int n) {
  int tid = threadIdx.x, lane = tid & 63, wv = tid >> 6;
  int i = blockIdx.x * 256 + tid;
  int v = (i < n) ? degi[i] : 0;
  int inc = v;
  #pragma unroll
  for (int ofs = 1; ofs < 64; ofs <<= 1) {
    int t = __shfl_up(inc, ofs, 64);
    if (lane >= ofs) inc += t;
  }
  __shared__ int wsum[4], woff[4];
  if (lane == 63) wsum[wv] = inc;
  __syncthreads();
  if (tid == 0) {
    int a = 0;
    for (int w = 0; w < 4; ++w) { woff[w] = a; a += wsum[w]; }
  }
  __syncthreads();
  if (i < n) ptr[i] = bofs[blockIdx.x] + woff[wv] + inc - v;
}

// ---------- CSR fill ----------
__global__ void fill_kernel(const int* __restrict__ src, const int* __restrict__ dst,
    const float* __restrict__ dinv, const int* __restrict__ ptr,
    int* __restrict__ fillc, int2* __restrict__ csr, int E) {
  int e = blockIdx.x * 256 + threadIdx.x;
  if (e >= E) return;
  int s = src[e], d = dst[e];
  int pos = ptr[d] + atomicAdd(&fillc[d], 1);
  float c = dinv[s] * dinv[d];
  csr[pos] = make_int2(s, __float_as_int(c));
}

// ---------- GEMM (optionally fused BN-apply/leaky/residual staging), bf16 out ----------
template<bool FUSED, bool WRITEX, bool TWOW>
__global__ __launch_bounds__(256) void gemm_kernel(
    const float* __restrict__ A,           // plain input or z (if FUSED)
    const float* __restrict__ scale, const float* __restrict__ shift,
    const float* __restrict__ xres, float* __restrict__ xout,
    const float* __restrict__ W0, const float* __restrict__ W1,
    ushort* __restrict__ Cbf, int n) {
  __shared__ float sW[128 * 128];
  __shared__ float sA[32 * 128];
  const int tid = threadIdx.x;
  for (int i = tid * 4; i < 128 * 128; i += 256 * 4) {
    float4 wv;
    if (TWOW) {
      int k = i >> 7, c = i & 127;
      wv = (c < 64) ? *(const float4*)&W0[k * 64 + c]
                    : *(const float4*)&W1[k * 64 + (c - 64)];
    } else {
      wv = *(const float4*)&W0[i];
    }
    *(float4*)&sW[i] = wv;
  }
  const int row0 = blockIdx.x * 32;
  #pragma unroll
  for (int j = 0; j < 4; ++j) {
    int fi = (tid + 256 * j) * 4;
    int r = fi >> 7, k = fi & 127;
    int row = row0 + r;
    float4 a = make_float4(0.f, 0.f, 0.f, 0.f);
    if (row < n) {
      if (FUSED) {
        float4 zv = *(const float4*)&A[(size_t)row * 128 + k];
        float4 xr = *(const float4*)&xres[(size_t)row * 128 + k];
        float4 sc = *(const float4*)&scale[k];
        float4 sh = *(const float4*)&shift[k];
        float u;
        u = fmaf(zv.x, sc.x, sh.x); u = u >= 0.f ? u : SLOPE * u; a.x = u + xr.x;
        u = fmaf(zv.y, sc.y, sh.y); u = u >= 0.f ? u : SLOPE * u; a.y = u + xr.y;
        u = fmaf(zv.z, sc.z, sh.z); u = u >= 0.f ? u : SLOPE * u; a.z = u + xr.z;
        u = fmaf(zv.w, sc.w, sh.w); u = u >= 0.f ? u : SLOPE * u; a.w = u + xr.w;
        if (WRITEX) *(float4*)&xout[(size_t)row * 128 + k] = a;
      } else {
        a = *(const float4*)&A[(size_t)row * 128 + k];
      }
    }
    *(float4*)&sA[r * 128 + k] = a;
  }
  __syncthreads();
  const int ty = tid >> 5;
  const int tx = tid & 31;
  float acc[4][4];
  #pragma unroll
  for (int r = 0; r < 4; ++r)
    #pragma unroll
    for (int c = 0; c < 4; ++c) acc[r][c] = 0.f;
  for (int k = 0; k < 128; k += 4) {
    float4 a[4];
    #pragma unroll
    for (int r = 0; r < 4; ++r) a[r] = *(const float4*)&sA[(ty * 4 + r) * 128 + k];
    #pragma unroll
    for (int kk = 0; kk < 4; ++kk) {
      #pragma unroll
      for (int c = 0; c < 4; ++c) {
        float wv = sW[(k + kk) * 128 + tx + 32 * c];
        #pragma unroll
        for (int r = 0; r < 4; ++r)
          acc[r][c] = fmaf(((const float*)&a[r])[kk], wv, acc[r][c]);
      }
    }
  }
  #pragma unroll
  for (int r = 0; r < 4; ++r) {
    int row = row0 + ty * 4 + r;
    if (row < n) {
      #pragma unroll
      for (int c = 0; c < 4; ++c)
        Cbf[(size_t)row * 128 + tx + 32 * c] = f2bf(acc[r][c]);
    }
  }
}

// ---------- gather propagate + fused BN partial stats ----------
// grid-stride over nodes; per-block 128-channel partial sum/sumsq written at end.
__global__ __launch_bounds__(256) void gather_layer(const int* __restrict__ ptr,
    const int2* __restrict__ csr, const uint* __restrict__ ybf,
    const float* __restrict__ b, const float* __restrict__ dinv,
    float* __restrict__ z, float* __restrict__ psum, float* __restrict__ psq, int n) {
  const int tid = threadIdx.x;
  const int lane = tid & 63, wv = tid >> 6;
  float2 bb = *(const float2*)&b[lane * 2];
  float sx = 0.f, sy = 0.f, qx = 0.f, qy = 0.f;
  const int wstride = gridDim.x * 4;
  for (int w = blockIdx.x * 4 + wv; w < n; w += wstride) {
    float dv = dinv[w], c0 = dv * dv;
    uint yv = ybf[(size_t)w * 64 + lane];
    float2 acc;
    acc.x = fmaf(c0, bf_lo(yv), bb.x);
    acc.y = fmaf(c0, bf_hi(yv), bb.y);
    int j = ptr[w], end = ptr[w + 1];
    for (; j + 1 < end; j += 2) {
      int2 e0 = csr[j], e1 = csr[j + 1];
      uint v0 = ybf[(size_t)e0.x * 64 + lane];
      uint v1 = ybf[(size_t)e1.x * 64 + lane];
      float cf0 = __int_as_float(e0.y), cf1 = __int_as_float(e1.y);
      acc.x = fmaf(cf0, bf_lo(v0), acc.x); acc.y = fmaf(cf0, bf_hi(v0), acc.y);
      acc.x = fmaf(cf1, bf_lo(v1), acc.x); acc.y = fmaf(cf1, bf_hi(v1), acc.y);
    }
    if (j < end) {
      int2 e0 = csr[j];
      uint v0 = ybf[(size_t)e0.x * 64 + lane];
      float cf = __int_as_float(e0.y);
      acc.x = fmaf(cf, bf_lo(v0), acc.x); acc.y = fmaf(cf, bf_hi(v0), acc.y);
    }
    *(float2*)&z[(size_t)w * 128 + lane * 2] = acc;
    sx += acc.x; sy += acc.y;
    qx = fmaf(acc.x, acc.x, qx); qy = fmaf(acc.y, acc.y, qy);
  }
  __shared__ float red[4][64];
  red[wv][lane] = sx; __syncthreads();
  if (wv == 0) psum[(size_t)blockIdx.x * 128 + lane * 2] =
      red[0][lane] + red[1][lane] + red[2][lane] + red[3][lane];
  __syncthreads();
  red[wv][lane] = sy; __syncthreads();
  if (wv == 0) psum[(size_t)blockIdx.x * 128 + lane * 2 + 1] =
      red[0][lane] + red[1][lane] + red[2][lane] + red[3][lane];
  __syncthreads();
  red[wv][lane] = qx; __syncthreads();
  if (wv == 0) psq[(size_t)blockIdx.x * 128 + lane * 2] =
      red[0][lane] + red[1][lane] + red[2][lane] + red[3][lane];
  __syncthreads();
  red[wv][lane] = qy; __syncthreads();
  if (wv == 0) psq[(size_t)blockIdx.x * 128 + lane * 2 + 1] =
      red[0][lane] + red[1][lane] + red[2][lane] + red[3][lane];
}

// ---------- heads gather: cols 0-63 -> mu, 64-127 -> logvar ----------
__global__ __launch_bounds__(256) void gather_heads(const int* __restrict__ ptr,
    const int2* __restrict__ csr, const uint* __restrict__ ybf,
    const float* __restrict__ bmu, const float* __restrict__ blv,
    const float* __restrict__ dinv, float* __restrict__ out, int n) {
  int w = (blockIdx.x * 256 + threadIdx.x) >> 6;
  if (w >= n) return;
  int lane = threadIdx.x & 63;
  int col = lane * 2;
  float* obase; const float* bias; int cc;
  if (col < 64) { obase = out; bias = bmu; cc = col; }
  else { obase = out + (size_t)n * 64; bias = blv; cc = col - 64; }
  float dv = dinv[w], c0 = dv * dv;
  uint yv = ybf[(size_t)w * 64 + lane];
  float2 acc;
  acc.x = fmaf(c0, bf_lo(yv), bias[cc]);
  acc.y = fmaf(c0, bf_hi(yv), bias[cc + 1]);
  int j = ptr[w], end = ptr[w + 1];
  for (; j + 1 < end; j += 2) {
    int2 e0 = csr[j], e1 = csr[j + 1];
    uint v0 = ybf[(size_t)e0.x * 64 + lane];
    uint v1 = ybf[(size_t)e1.x * 64 + lane];
    float cf0 = __int_as_float(e0.y), cf1 = __int_as_float(e1.y);
    acc.x = fmaf(cf0, bf_lo(v0), acc.x); acc.y = fmaf(cf0, bf_hi(v0), acc.y);
    acc.x = fmaf(cf1, bf_lo(v1), acc.x); acc.y = fmaf(cf1, bf_hi(v1), acc.y);
  }
  if (j < end) {
    int2 e0 = csr[j];
    uint v0 = ybf[(size_t)e0.x * 64 + lane];
    float cf = __int_as_float(e0.y);
    acc.x = fmaf(cf, bf_lo(v0), acc.x); acc.y = fmaf(cf, bf_hi(v0), acc.y);
  }
  *(float2*)&obase[(size_t)w * 64 + cc] = acc;
}

// ---------- BN finalize: 128 blocks (one per channel) x 256 threads ----------
__global__ __launch_bounds__(256) void bnfin_kernel(const float* __restrict__ psum,
    const float* __restrict__ psq, const float* __restrict__ gamma,
    const float* __restrict__ beta, float* __restrict__ scale,
    float* __restrict__ shift, int n, int nb) {
  const int c = blockIdx.x;
  const int tid = threadIdx.x;
  float s = 0.f, s2 = 0.f;
  for (int b = tid; b < nb; b += 256) {
    s += psum[(size_t)b * 128 + c];
    s2 += psq[(size_t)b * 128 + c];
  }
  #pragma unroll
  for (int ofs = 32; ofs; ofs >>= 1) {
    s += __shfl_down(s, ofs, 64);
    s2 += __shfl_down(s2, ofs, 64);
  }
  __shared__ float ws[4], wq[4];
  if ((tid & 63) == 0) { ws[tid >> 6] = s; wq[tid >> 6] = s2; }
  __syncthreads();
  if (tid == 0) {
    float S = ws[0] + ws[1] + ws[2] + ws[3];
    float Q = wq[0] + wq[1] + wq[2] + wq[3];
    float mean = S / (float)n;
    float var = Q / (float)n - mean * mean;
    float inv = rsqrtf(var + EPS);
    float sc = gamma[c] * inv;
    scale[c] = sc;
    shift[c] = beta[c] - mean * sc;
  }
}

extern "C" void kernel_launch(void* const* d_in, const int* in_sizes, int n_in,
                              void* d_out, int out_size, void* d_ws, size_t ws_size,
                              hipStream_t stream) {
  const float* x     = (const float*)d_in[0];
  const int*   ei    = (const int*)d_in[1];
  const float* Ws    = (const float*)d_in[2];
  const float* bs    = (const float*)d_in[3];
  const float* Wmu   = (const float*)d_in[4];
  const float* bmu   = (const float*)d_in[5];
  const float* Wlv   = (const float*)d_in[6];
  const float* blv   = (const float*)d_in[7];
  const float* gamma = (const float*)d_in[8];
  const float* beta  = (const float*)d_in[9];
  float* out = (float*)d_out;

  const int n = in_sizes[0] / 128;
  const int E = in_sizes[1] / 2;
  const int* srcI = ei;
  const int* dstI = ei + E;
  const int nb = cdiv(n, 256);

  char* wsp = (char*)d_ws;
  size_t off = 0;
  auto alloc = [&](size_t bytes) -> void* {
    void* p = wsp + off;
    off += (bytes + 255) & ~(size_t)255;
    return p;
  };
  int*    degi  = (int*)alloc((size_t)n * 4);
  float*  dinv  = (float*)alloc((size_t)n * 4);
  int*    ptr   = (int*)alloc((size_t)(n + 1) * 4);
  int*    fillc = (int*)alloc((size_t)n * 4);
  int*    bsum  = (int*)alloc((size_t)nb * 4);
  int*    bofs  = (int*)alloc((size_t)nb * 4);
  int2*   csr   = (int2*)alloc((size_t)E * 8);
  ushort* ybf   = (ushort*)alloc((size_t)n * 128 * 2);
  float*  z     = (float*)alloc((size_t)n * 128 * 4);
  float*  xbuf  = (float*)alloc((size_t)n * 128 * 4);
  float*  psum  = (float*)alloc((size_t)GATHER_BLOCKS * 128 * 4);
  float*  psq   = (float*)alloc((size_t)GATHER_BLOCKS * 128 * 4);
  float*  scale = (float*)alloc(128 * 4);
  float*  shift = (float*)alloc(128 * 4);
  (void)n_in; (void)out_size; (void)ws_size;

  hipMemsetAsync(degi, 0, (size_t)n * 4, stream);
  hipMemsetAsync(fillc, 0, (size_t)n * 4, stream);
  deg_kernel<<<cdiv(E, 256), 256, 0, stream>>>(dstI, degi, E);
  dinv_kernel<<<cdiv(n, 256), 256, 0, stream>>>(degi, dinv, n);
  bsum_kernel<<<nb, 256, 0, stream>>>(degi, bsum, n);
  bscan_kernel<<<1, 256, 0, stream>>>(bsum, bofs, ptr + n, nb);
  ptr_kernel<<<nb, 256, 0, stream>>>(degi, bofs, ptr, n);
  fill_kernel<<<cdiv(E, 256), 256, 0, stream>>>(srcI, dstI, dinv, ptr, fillc, csr, E);

  const int ggrid = cdiv(n, 32);
  const int wgrid = cdiv((long)n * 64, 256);

  // layer 0
  gemm_kernel<false, false, false><<<ggrid, 256, 0, stream>>>(
      x, nullptr, nullptr, nullptr, nullptr, Ws, nullptr, ybf, n);
  gather_layer<<<GATHER_BLOCKS, 256, 0, stream>>>(ptr, csr, (const uint*)ybf, bs, dinv, z, psum, psq, n);
  bnfin_kernel<<<128, 256, 0, stream>>>(psum, psq, gamma, beta, scale, shift, n, GATHER_BLOCKS);
  // layer 1 (staging applies BN+leaky+res with xres=x, writes xbuf)
  gemm_kernel<true, true, false><<<ggrid, 256, 0, stream>>>(
      z, scale, shift, x, xbuf, Ws + 16384, nullptr, ybf, n);
  gather_layer<<<GATHER_BLOCKS, 256, 0, stream>>>(ptr, csr, (const uint*)ybf, bs + 128, dinv, z, psum, psq, n);
  bnfin_kernel<<<128, 256, 0, stream>>>(psum, psq, gamma, beta, scale, shift, n, GATHER_BLOCKS);
  // layer 2 (xres=xbuf, update xbuf in place; each block touches only its own rows)
  gemm_kernel<true, true, false><<<ggrid, 256, 0, stream>>>(
      z, scale, shift, xbuf, xbuf, Ws + 32768, nullptr, ybf, n);
  gather_layer<<<GATHER_BLOCKS, 256, 0, stream>>>(ptr, csr, (const uint*)ybf, bs + 256, dinv, z, psum, psq, n);
  bnfin_kernel<<<128, 256, 0, stream>>>(psum, psq, gamma, beta, scale, shift, n, GATHER_BLOCKS);
  // heads: one GEMM with W = [Wmu | Wlv], one gather writing both outputs
  gemm_kernel<true, false, true><<<ggrid, 256, 0, stream>>>(
      z, scale, shift, xbuf, nullptr, Wmu, Wlv, ybf, n);
  gather_heads<<<wgrid, 256, 0, stream>>>(ptr, csr, (const uint*)ybf, bmu, blv, dinv, out, n);
}

// Round 5
// 350.639 us; speedup vs baseline: 13.6039x; 1.2683x over previous
//
#include <hip/hip_runtime.h>

typedef unsigned int uint;
typedef unsigned short ushort;

#define EPS 1e-5f
#define SLOPE 0.01f
#define GATHER_BLOCKS 2048
#define PK 136   // padded k-stride (bf16 elems) for LDS W^T

static inline int cdiv(long a, int b) { return (int)((a + b - 1) / b); }

typedef __attribute__((ext_vector_type(8))) short short8;
typedef __attribute__((ext_vector_type(4))) float f32x4;

__device__ inline float bf_lo(uint v) { return __uint_as_float(v << 16); }
__device__ inline float bf_hi(uint v) { return __uint_as_float(v & 0xffff0000u); }
__device__ inline ushort f2bf(float f) {
  uint u = __float_as_uint(f);
  u += 0x7fffu + ((u >> 16) & 1u);   // RNE
  return (ushort)(u >> 16);
}

// ---------- degree ----------
__global__ void deg_kernel(const int* __restrict__ dst, int* __restrict__ degi, int E) {
  int e = blockIdx.x * 256 + threadIdx.x;
  if (e < E) atomicAdd(&degi[dst[e]], 1);
}

__global__ void dinv_kernel(const int* __restrict__ degi, float* __restrict__ dinv, int n) {
  int v = blockIdx.x * 256 + threadIdx.x;
  if (v < n) dinv[v] = rsqrtf((float)(degi[v] + 1));  // +1 self-loop
}

// ---------- parallel exclusive scan ----------
__global__ __launch_bounds__(256) void bsum_kernel(const int* __restrict__ degi,
    int* __restrict__ bsum, int n) {
  int tid = threadIdx.x;
  int i = blockIdx.x * 256 + tid;
  int v = (i < n) ? degi[i] : 0;
  #pragma unroll
  for (int ofs = 32; ofs; ofs >>= 1) v += __shfl_down(v, ofs, 64);
  __shared__ int ws[4];
  if ((tid & 63) == 0) ws[tid >> 6] = v;
  __syncthreads();
  if (tid == 0) bsum[blockIdx.x] = ws[0] + ws[1] + ws[2] + ws[3];
}

__global__ __launch_bounds__(256) void bscan_kernel(const int* __restrict__ bsum,
    int* __restrict__ bofs, int* __restrict__ ptr_end, int nb) {
  int tid = threadIdx.x, lane = tid & 63, wv = tid >> 6;
  __shared__ int wsum[4];
  __shared__ int carry_s, tot_s;
  if (tid == 0) carry_s = 0;
  __syncthreads();
  for (int base = 0; base < nb; base += 256) {
    int i = base + tid;
    int v = (i < nb) ? bsum[i] : 0;
    int inc = v;
    #pragma unroll
    for (int ofs = 1; ofs < 64; ofs <<= 1) {
      int t = __shfl_up(inc, ofs, 64);
      if (lane >= ofs) inc += t;
    }
    if (lane == 63) wsum[wv] = inc;
    __syncthreads();
    if (tid == 0) {
      int a = carry_s;
      for (int w = 0; w < 4; ++w) { int t = wsum[w]; wsum[w] = a; a += t; }
      tot_s = a;
    }
    __syncthreads();
    if (i < nb) bofs[i] = wsum[wv] + inc - v;
    __syncthreads();
    if (tid == 0) carry_s = tot_s;
    __syncthreads();
  }
  if (tid == 0) *ptr_end = carry_s;
}

__global__ __launch_bounds__(256) void ptr_kernel(const int* __restrict__ degi,
    const int* __restrict__ bofs, int* __restrict__ ptr, int n) {
  int tid = threadIdx.x, lane = tid & 63, wv = tid >> 6;
  int i = blockIdx.x * 256 + tid;
  int v = (i < n) ? degi[i] : 0;
  int inc = v;
  #pragma unroll
  for (int ofs = 1; ofs < 64; ofs <<= 1) {
    int t = __shfl_up(inc, ofs, 64);
    if (lane >= ofs) inc += t;
  }
  __shared__ int wsum[4], woff[4];
  if (lane == 63) wsum[wv] = inc;
  __syncthreads();
  if (tid == 0) {
    int a = 0;
    for (int w = 0; w < 4; ++w) { woff[w] = a; a += wsum[w]; }
  }
  __syncthreads();
  if (i < n) ptr[i] = bofs[blockIdx.x] + woff[wv] + inc - v;
}

// ---------- CSR fill ----------
__global__ void fill_kernel(const int* __restrict__ src, const int* __restrict__ dst,
    const float* __restrict__ dinv, const int* __restrict__ ptr,
    int* __restrict__ fillc, int2* __restrict__ csr, int E) {
  int e = blockIdx.x * 256 + threadIdx.x;
  if (e >= E) return;
  int s = src[e], d = dst[e];
  int pos = ptr[d] + atomicAdd(&fillc[d], 1);
  float c = dinv[s] * dinv[d];
  csr[pos] = make_int2(s, __float_as_int(c));
}

// ---------- MFMA GEMM: C_bf16[n][128] = A[n][128] @ W[128][128] ----------
// block = 128 rows, 4 waves x (2 M-tiles of 16); W^T staged bf16 in LDS.
// FUSED: A := leaky(A*scale+shift)+xres  (and optionally written to xout)
template<bool FUSED, bool WRITEX, bool TWOW>
__global__ __launch_bounds__(256) void mfma_gemm(
    const float* __restrict__ A,
    const float* __restrict__ scale, const float* __restrict__ shift,
    const float* __restrict__ xres, float* __restrict__ xout,
    const float* __restrict__ W0, const float* __restrict__ W1,
    ushort* __restrict__ Cbf, int n) {
  __shared__ ushort sWt[128 * PK];
  const int tid = threadIdx.x;
  // ---- stage W^T (bf16) : 4x4 tile transpose per thread-iter ----
  for (int t = tid; t < 1024; t += 256) {
    const int tk = t & 31;          // k-tile (lane-consecutive -> 2-way LDS writes)
    const int tc = t >> 5;          // col-tile
    float4 r0, r1, r2, r3;
    if (TWOW) {
      int c = tc * 4;
      const float* Wb = (c < 64) ? W0 : W1;
      int cc = (c < 64) ? c : c - 64;
      r0 = *(const float4*)&Wb[(tk * 4 + 0) * 64 + cc];
      r1 = *(const float4*)&Wb[(tk * 4 + 1) * 64 + cc];
      r2 = *(const float4*)&Wb[(tk * 4 + 2) * 64 + cc];
      r3 = *(const float4*)&Wb[(tk * 4 + 3) * 64 + cc];
    } else {
      r0 = *(const float4*)&W0[(tk * 4 + 0) * 128 + tc * 4];
      r1 = *(const float4*)&W0[(tk * 4 + 1) * 128 + tc * 4];
      r2 = *(const float4*)&W0[(tk * 4 + 2) * 128 + tc * 4];
      r3 = *(const float4*)&W0[(tk * 4 + 3) * 128 + tc * 4];
    }
    const float* p0 = (const float*)&r0;
    const float* p1 = (const float*)&r1;
    const float* p2 = (const float*)&r2;
    const float* p3 = (const float*)&r3;
    #pragma unroll
    for (int j = 0; j < 4; ++j) {
      uint lo = (uint)f2bf(p0[j]) | ((uint)f2bf(p1[j]) << 16);
      uint hi = (uint)f2bf(p2[j]) | ((uint)f2bf(p3[j]) << 16);
      *(uint2*)&sWt[(tc * 4 + j) * PK + tk * 4] = make_uint2(lo, hi);
    }
  }
  __syncthreads();

  const int w = tid >> 6;
  const int lane = tid & 63;
  const int l16 = lane & 15, q = lane >> 4;
  const int row0 = blockIdx.x * 128 + w * 32;

  f32x4 acc[2][8];
  #pragma unroll
  for (int mt = 0; mt < 2; ++mt)
    #pragma unroll
    for (int nt = 0; nt < 8; ++nt)
      acc[mt][nt] = (f32x4){0.f, 0.f, 0.f, 0.f};

  for (int ks = 0; ks < 4; ++ks) {
    const int kbase = ks * 32 + q * 8;
    short8 afrag[2];
    #pragma unroll
    for (int mt = 0; mt < 2; ++mt) {
      int row = row0 + mt * 16 + l16;
      float4 a0 = make_float4(0.f, 0.f, 0.f, 0.f);
      float4 a1 = make_float4(0.f, 0.f, 0.f, 0.f);
      if (row < n) {
        const float* Ar = A + (size_t)row * 128 + kbase;
        if constexpr (FUSED) {
          float4 z0 = *(const float4*)&Ar[0];
          float4 z1 = *(const float4*)&Ar[4];
          float4 sc0 = *(const float4*)&scale[kbase];
          float4 sc1 = *(const float4*)&scale[kbase + 4];
          float4 sh0 = *(const float4*)&shift[kbase];
          float4 sh1 = *(const float4*)&shift[kbase + 4];
          const float* Xr = xres + (size_t)row * 128 + kbase;
          float4 x0 = *(const float4*)&Xr[0];
          float4 x1 = *(const float4*)&Xr[4];
          float u;
          u = fmaf(z0.x, sc0.x, sh0.x); u = u >= 0.f ? u : SLOPE * u; a0.x = u + x0.x;
          u = fmaf(z0.y, sc0.y, sh0.y); u = u >= 0.f ? u : SLOPE * u; a0.y = u + x0.y;
          u = fmaf(z0.z, sc0.z, sh0.z); u = u >= 0.f ? u : SLOPE * u; a0.z = u + x0.z;
          u = fmaf(z0.w, sc0.w, sh0.w); u = u >= 0.f ? u : SLOPE * u; a0.w = u + x0.w;
          u = fmaf(z1.x, sc1.x, sh1.x); u = u >= 0.f ? u : SLOPE * u; a1.x = u + x1.x;
          u = fmaf(z1.y, sc1.y, sh1.y); u = u >= 0.f ? u : SLOPE * u; a1.y = u + x1.y;
          u = fmaf(z1.z, sc1.z, sh1.z); u = u >= 0.f ? u : SLOPE * u; a1.z = u + x1.z;
          u = fmaf(z1.w, sc1.w, sh1.w); u = u >= 0.f ? u : SLOPE * u; a1.w = u + x1.w;
          if constexpr (WRITEX) {
            float* Xo = xout + (size_t)row * 128 + kbase;
            *(float4*)&Xo[0] = a0;
            *(float4*)&Xo[4] = a1;
          }
        } else {
          a0 = *(const float4*)&Ar[0];
          a1 = *(const float4*)&Ar[4];
        }
      }
      short8 af;
      af[0] = (short)f2bf(a0.x); af[1] = (short)f2bf(a0.y);
      af[2] = (short)f2bf(a0.z); af[3] = (short)f2bf(a0.w);
      af[4] = (short)f2bf(a1.x); af[5] = (short)f2bf(a1.y);
      af[6] = (short)f2bf(a1.z); af[7] = (short)f2bf(a1.w);
      afrag[mt] = af;
    }
    #pragma unroll
    for (int nt = 0; nt < 8; ++nt) {
      short8 bfrag = *(const short8*)&sWt[(nt * 16 + l16) * PK + kbase];
      acc[0][nt] = __builtin_amdgcn_mfma_f32_16x16x32_bf16(afrag[0], bfrag, acc[0][nt], 0, 0, 0);
      acc[1][nt] = __builtin_amdgcn_mfma_f32_16x16x32_bf16(afrag[1], bfrag, acc[1][nt], 0, 0, 0);
    }
  }
  // epilogue: D row = (lane>>4)*4 + reg, col = lane&15
  #pragma unroll
  for (int mt = 0; mt < 2; ++mt) {
    int rbase = row0 + mt * 16 + q * 4;
    #pragma unroll
    for (int nt = 0; nt < 8; ++nt) {
      int col = nt * 16 + l16;
      #pragma unroll
      for (int r = 0; r < 4; ++r) {
        int row = rbase + r;
        if (row < n) Cbf[(size_t)row * 128 + col] = f2bf(acc[mt][nt][r]);
      }
    }
  }
}

// ---------- gather propagate + fused BN partial stats ----------
__global__ __launch_bounds__(256) void gather_layer(const int* __restrict__ ptr,
    const int2* __restrict__ csr, const uint* __restrict__ ybf,
    const float* __restrict__ b, const float* __restrict__ dinv,
    float* __restrict__ z, float* __restrict__ psum, float* __restrict__ psq, int n) {
  const int tid = threadIdx.x;
  const int lane = tid & 63, wv = tid >> 6;
  float2 bb = *(const float2*)&b[lane * 2];
  float sx = 0.f, sy = 0.f, qx = 0.f, qy = 0.f;
  const int wstride = gridDim.x * 4;
  for (int w = blockIdx.x * 4 + wv; w < n; w += wstride) {
    float dv = dinv[w], c0 = dv * dv;
    uint yv = ybf[(size_t)w * 64 + lane];
    float2 acc;
    acc.x = fmaf(c0, bf_lo(yv), bb.x);
    acc.y = fmaf(c0, bf_hi(yv), bb.y);
    int j = ptr[w], end = ptr[w + 1];
    for (; j + 1 < end; j += 2) {
      int2 e0 = csr[j], e1 = csr[j + 1];
      uint v0 = ybf[(size_t)e0.x * 64 + lane];
      uint v1 = ybf[(size_t)e1.x * 64 + lane];
      float cf0 = __int_as_float(e0.y), cf1 = __int_as_float(e1.y);
      acc.x = fmaf(cf0, bf_lo(v0), acc.x); acc.y = fmaf(cf0, bf_hi(v0), acc.y);
      acc.x = fmaf(cf1, bf_lo(v1), acc.x); acc.y = fmaf(cf1, bf_hi(v1), acc.y);
    }
    if (j < end) {
      int2 e0 = csr[j];
      uint v0 = ybf[(size_t)e0.x * 64 + lane];
      float cf = __int_as_float(e0.y);
      acc.x = fmaf(cf, bf_lo(v0), acc.x); acc.y = fmaf(cf, bf_hi(v0), acc.y);
    }
    *(float2*)&z[(size_t)w * 128 + lane * 2] = acc;
    sx += acc.x; sy += acc.y;
    qx = fmaf(acc.x, acc.x, qx); qy = fmaf(acc.y, acc.y, qy);
  }
  __shared__ float red[4][64];
  red[wv][lane] = sx; __syncthreads();
  if (wv == 0) psum[(size_t)blockIdx.x * 128 + lane * 2] =
      red[0][lane] + red[1][lane] + red[2][lane] + red[3][lane];
  __syncthreads();
  red[wv][lane] = sy; __syncthreads();
  if (wv == 0) psum[(size_t)blockIdx.x * 128 + lane * 2 + 1] =
      red[0][lane] + red[1][lane] + red[2][lane] + red[3][lane];
  __syncthreads();
  red[wv][lane] = qx; __syncthreads();
  if (wv == 0) psq[(size_t)blockIdx.x * 128 + lane * 2] =
      red[0][lane] + red[1][lane] + red[2][lane] + red[3][lane];
  __syncthreads();
  red[wv][lane] = qy; __syncthreads();
  if (wv == 0) psq[(size_t)blockIdx.x * 128 + lane * 2 + 1] =
      red[0][lane] + red[1][lane] + red[2][lane] + red[3][lane];
}

// ---------- heads gather ----------
__global__ __launch_bounds__(256) void gather_heads(const int* __restrict__ ptr,
    const int2* __restrict__ csr, const uint* __restrict__ ybf,
    const float* __restrict__ bmu, const float* __restrict__ blv,
    const float* __restrict__ dinv, float* __restrict__ out, int n) {
  int w = (blockIdx.x * 256 + threadIdx.x) >> 6;
  if (w >= n) return;
  int lane = threadIdx.x & 63;
  int col = lane * 2;
  float* obase; const float* bias; int cc;
  if (col < 64) { obase = out; bias = bmu; cc = col; }
  else { obase = out + (size_t)n * 64; bias = blv; cc = col - 64; }
  float dv = dinv[w], c0 = dv * dv;
  uint yv = ybf[(size_t)w * 64 + lane];
  float2 acc;
  acc.x = fmaf(c0, bf_lo(yv), bias[cc]);
  acc.y = fmaf(c0, bf_hi(yv), bias[cc + 1]);
  int j = ptr[w], end = ptr[w + 1];
  for (; j + 1 < end; j += 2) {
    int2 e0 = csr[j], e1 = csr[j + 1];
    uint v0 = ybf[(size_t)e0.x * 64 + lane];
    uint v1 = ybf[(size_t)e1.x * 64 + lane];
    float cf0 = __int_as_float(e0.y), cf1 = __int_as_float(e1.y);
    acc.x = fmaf(cf0, bf_lo(v0), acc.x); acc.y = fmaf(cf0, bf_hi(v0), acc.y);
    acc.x = fmaf(cf1, bf_lo(v1), acc.x); acc.y = fmaf(cf1, bf_hi(v1), acc.y);
  }
  if (j < end) {
    int2 e0 = csr[j];
    uint v0 = ybf[(size_t)e0.x * 64 + lane];
    float cf = __int_as_float(e0.y);
    acc.x = fmaf(cf, bf_lo(v0), acc.x); acc.y = fmaf(cf, bf_hi(v0), acc.y);
  }
  *(float2*)&obase[(size_t)w * 64 + cc] = acc;
}

// ---------- BN finalize: 128 blocks (one per channel) ----------
__global__ __launch_bounds__(256) void bnfin_kernel(const float* __restrict__ psum,
    const float* __restrict__ psq, const float* __restrict__ gamma,
    const float* __restrict__ beta, float* __restrict__ scale,
    float* __restrict__ shift, int n, int nb) {
  const int c = blockIdx.x;
  const int tid = threadIdx.x;
  float s = 0.f, s2 = 0.f;
  for (int b = tid; b < nb; b += 256) {
    s += psum[(size_t)b * 128 + c];
    s2 += psq[(size_t)b * 128 + c];
  }
  #pragma unroll
  for (int ofs = 32; ofs; ofs >>= 1) {
    s += __shfl_down(s, ofs, 64);
    s2 += __shfl_down(s2, ofs, 64);
  }
  __shared__ float ws[4], wq[4];
  if ((tid & 63) == 0) { ws[tid >> 6] = s; wq[tid >> 6] = s2; }
  __syncthreads();
  if (tid == 0) {
    float S = ws[0] + ws[1] + ws[2] + ws[3];
    float Q = wq[0] + wq[1] + wq[2] + wq[3];
    float mean = S / (float)n;
    float var = Q / (float)n - mean * mean;
    float inv = rsqrtf(var + EPS);
    float sc = gamma[c] * inv;
    scale[c] = sc;
    shift[c] = beta[c] - mean * sc;
  }
}

extern "C" void kernel_launch(void* const* d_in, const int* in_sizes, int n_in,
                              void* d_out, int out_size, void* d_ws, size_t ws_size,
                              hipStream_t stream) {
  const float* x     = (const float*)d_in[0];
  const int*   ei    = (const int*)d_in[1];
  const float* Ws    = (const float*)d_in[2];
  const float* bs    = (const float*)d_in[3];
  const float* Wmu   = (const float*)d_in[4];
  const float* bmu   = (const float*)d_in[5];
  const float* Wlv   = (const float*)d_in[6];
  const float* blv   = (const float*)d_in[7];
  const float* gamma = (const float*)d_in[8];
  const float* beta  = (const float*)d_in[9];
  float* out = (float*)d_out;

  const int n = in_sizes[0] / 128;
  const int E = in_sizes[1] / 2;
  const int* srcI = ei;
  const int* dstI = ei + E;
  const int nb = cdiv(n, 256);

  char* wsp = (char*)d_ws;
  size_t off = 0;
  auto alloc = [&](size_t bytes) -> void* {
    void* p = wsp + off;
    off += (bytes + 255) & ~(size_t)255;
    return p;
  };
  int*    degi  = (int*)alloc((size_t)n * 4);
  float*  dinv  = (float*)alloc((size_t)n * 4);
  int*    ptr   = (int*)alloc((size_t)(n + 1) * 4);
  int*    fillc = (int*)alloc((size_t)n * 4);
  int*    bsum  = (int*)alloc((size_t)nb * 4);
  int*    bofs  = (int*)alloc((size_t)nb * 4);
  int2*   csr   = (int2*)alloc((size_t)E * 8);
  ushort* ybf   = (ushort*)alloc((size_t)n * 128 * 2);
  float*  z     = (float*)alloc((size_t)n * 128 * 4);
  float*  xbuf  = (float*)alloc((size_t)n * 128 * 4);
  float*  psum  = (float*)alloc((size_t)GATHER_BLOCKS * 128 * 4);
  float*  psq   = (float*)alloc((size_t)GATHER_BLOCKS * 128 * 4);
  float*  scale = (float*)alloc(128 * 4);
  float*  shift = (float*)alloc(128 * 4);
  (void)n_in; (void)out_size; (void)ws_size;

  hipMemsetAsync(degi, 0, (size_t)n * 4, stream);
  hipMemsetAsync(fillc, 0, (size_t)n * 4, stream);
  deg_kernel<<<cdiv(E, 256), 256, 0, stream>>>(dstI, degi, E);
  dinv_kernel<<<cdiv(n, 256), 256, 0, stream>>>(degi, dinv, n);
  bsum_kernel<<<nb, 256, 0, stream>>>(degi, bsum, n);
  bscan_kernel<<<1, 256, 0, stream>>>(bsum, bofs, ptr + n, nb);
  ptr_kernel<<<nb, 256, 0, stream>>>(degi, bofs, ptr, n);
  fill_kernel<<<cdiv(E, 256), 256, 0, stream>>>(srcI, dstI, dinv, ptr, fillc, csr, E);

  const int ggrid = cdiv(n, 128);
  const int wgrid = cdiv((long)n * 64, 256);

  // layer 0
  mfma_gemm<false, false, false><<<ggrid, 256, 0, stream>>>(
      x, nullptr, nullptr, nullptr, nullptr, Ws, nullptr, ybf, n);
  gather_layer<<<GATHER_BLOCKS, 256, 0, stream>>>(ptr, csr, (const uint*)ybf, bs, dinv, z, psum, psq, n);
  bnfin_kernel<<<128, 256, 0, stream>>>(psum, psq, gamma, beta, scale, shift, n, GATHER_BLOCKS);
  // layer 1 (fused BN+leaky+res with xres=x, writes xbuf)
  mfma_gemm<true, true, false><<<ggrid, 256, 0, stream>>>(
      z, scale, shift, x, xbuf, Ws + 16384, nullptr, ybf, n);
  gather_layer<<<GATHER_BLOCKS, 256, 0, stream>>>(ptr, csr, (const uint*)ybf, bs + 128, dinv, z, psum, psq, n);
  bnfin_kernel<<<128, 256, 0, stream>>>(psum, psq, gamma, beta, scale, shift, n, GATHER_BLOCKS);
  // layer 2 (xres=xbuf, in-place update of xbuf; each lane owns its elements)
  mfma_gemm<true, true, false><<<ggrid, 256, 0, stream>>>(
      z, scale, shift, xbuf, xbuf, Ws + 32768, nullptr, ybf, n);
  gather_layer<<<GATHER_BLOCKS, 256, 0, stream>>>(ptr, csr, (const uint*)ybf, bs + 256, dinv, z, psum, psq, n);
  bnfin_kernel<<<128, 256, 0, stream>>>(psum, psq, gamma, beta, scale, shift, n, GATHER_BLOCKS);
  // heads: one GEMM with W = [Wmu | Wlv], one gather writing both outputs
  mfma_gemm<true, false, true><<<ggrid, 256, 0, stream>>>(
      z, scale, shift, xbuf, nullptr, Wmu, Wlv, ybf, n);
  gather_heads<<<wgrid, 256, 0, stream>>>(ptr, csr, (const uint*)ybf, bmu, blv, dinv, out, n);
}

// Round 6
// 301.336 us; speedup vs baseline: 15.8297x; 1.1636x over previous
//
#include <hip/hip_runtime.h>

typedef unsigned int uint;
typedef unsigned short ushort;

#define EPS 1e-5f
#define SLOPE 0.01f
#define GATHER_BLOCKS 2048
#define PK 136   // padded k-stride (bf16 elems) for LDS W^T

static inline int cdiv(long a, int b) { return (int)((a + b - 1) / b); }

typedef __attribute__((ext_vector_type(8))) short short8;
typedef __attribute__((ext_vector_type(4))) float f32x4;

__device__ inline float bf_lo(uint v) { return __uint_as_float(v << 16); }
__device__ inline float bf_hi(uint v) { return __uint_as_float(v & 0xffff0000u); }
__device__ inline ushort f2bf(float f) {
  uint u = __float_as_uint(f);
  u += 0x7fffu + ((u >> 16) & 1u);   // RNE
  return (ushort)(u >> 16);
}
__device__ inline uint pack2bf(float a, float b) {
  return (uint)f2bf(a) | ((uint)f2bf(b) << 16);
}

// ---------- degree ----------
__global__ void deg_kernel(const int* __restrict__ dst, int* __restrict__ degi, int E) {
  int e = blockIdx.x * 256 + threadIdx.x;
  if (e < E) atomicAdd(&degi[dst[e]], 1);
}

__global__ void dinv_kernel(const int* __restrict__ degi, float* __restrict__ dinv, int n) {
  int v = blockIdx.x * 256 + threadIdx.x;
  if (v < n) dinv[v] = rsqrtf((float)(degi[v] + 1));  // +1 self-loop
}

// ---------- parallel exclusive scan ----------
__global__ __launch_bounds__(256) void bsum_kernel(const int* __restrict__ degi,
    int* __restrict__ bsum, int n) {
  int tid = threadIdx.x;
  int i = blockIdx.x * 256 + tid;
  int v = (i < n) ? degi[i] : 0;
  #pragma unroll
  for (int ofs = 32; ofs; ofs >>= 1) v += __shfl_down(v, ofs, 64);
  __shared__ int ws[4];
  if ((tid & 63) == 0) ws[tid >> 6] = v;
  __syncthreads();
  if (tid == 0) bsum[blockIdx.x] = ws[0] + ws[1] + ws[2] + ws[3];
}

__global__ __launch_bounds__(256) void bscan_kernel(const int* __restrict__ bsum,
    int* __restrict__ bofs, int* __restrict__ ptr_end, int nb) {
  int tid = threadIdx.x, lane = tid & 63, wv = tid >> 6;
  __shared__ int wsum[4];
  __shared__ int carry_s, tot_s;
  if (tid == 0) carry_s = 0;
  __syncthreads();
  for (int base = 0; base < nb; base += 256) {
    int i = base + tid;
    int v = (i < nb) ? bsum[i] : 0;
    int inc = v;
    #pragma unroll
    for (int ofs = 1; ofs < 64; ofs <<= 1) {
      int t = __shfl_up(inc, ofs, 64);
      if (lane >= ofs) inc += t;
    }
    if (lane == 63) wsum[wv] = inc;
    __syncthreads();
    if (tid == 0) {
      int a = carry_s;
      for (int w = 0; w < 4; ++w) { int t = wsum[w]; wsum[w] = a; a += t; }
      tot_s = a;
    }
    __syncthreads();
    if (i < nb) bofs[i] = wsum[wv] + inc - v;
    __syncthreads();
    if (tid == 0) carry_s = tot_s;
    __syncthreads();
  }
  if (tid == 0) *ptr_end = carry_s;
}

__global__ __launch_bounds__(256) void ptr_kernel(const int* __restrict__ degi,
    const int* __restrict__ bofs, int* __restrict__ ptr, int n) {
  int tid = threadIdx.x, lane = tid & 63, wv = tid >> 6;
  int i = blockIdx.x * 256 + tid;
  int v = (i < n) ? degi[i] : 0;
  int inc = v;
  #pragma unroll
  for (int ofs = 1; ofs < 64; ofs <<= 1) {
    int t = __shfl_up(inc, ofs, 64);
    if (lane >= ofs) inc += t;
  }
  __shared__ int wsum[4], woff[4];
  if (lane == 63) wsum[wv] = inc;
  __syncthreads();
  if (tid == 0) {
    int a = 0;
    for (int w = 0; w < 4; ++w) { woff[w] = a; a += wsum[w]; }
  }
  __syncthreads();
  if (i < n) ptr[i] = bofs[blockIdx.x] + woff[wv] + inc - v;
}

// ---------- CSR fill ----------
__global__ void fill_kernel(const int* __restrict__ src, const int* __restrict__ dst,
    const float* __restrict__ dinv, const int* __restrict__ ptr,
    int* __restrict__ fillc, int2* __restrict__ csr, int E) {
  int e = blockIdx.x * 256 + threadIdx.x;
  if (e >= E) return;
  int s = src[e], d = dst[e];
  int pos = ptr[d] + atomicAdd(&fillc[d], 1);
  float c = dinv[s] * dinv[d];
  csr[pos] = make_int2(s, __float_as_int(c));
}

// ---------- MFMA GEMM: C_bf16[n][128] = A[n][128] @ W[128][128] ----------
// FUSED: A comes from bf16-packed z; A := leaky(z*scale+shift)+xres
template<bool FUSED, bool WRITEX, bool TWOW>
__global__ __launch_bounds__(256) void mfma_gemm(
    const float* __restrict__ Af, const uint* __restrict__ Az,
    const float* __restrict__ scale, const float* __restrict__ shift,
    const float* __restrict__ xres, float* __restrict__ xout,
    const float* __restrict__ W0, const float* __restrict__ W1,
    ushort* __restrict__ Cbf, int n) {
  __shared__ ushort sWt[128 * PK];
  const int tid = threadIdx.x;
  // ---- stage W^T (bf16) ----
  for (int t = tid; t < 1024; t += 256) {
    const int tk = t & 31;
    const int tc = t >> 5;
    float4 r0, r1, r2, r3;
    if (TWOW) {
      int c = tc * 4;
      const float* Wb = (c < 64) ? W0 : W1;
      int cc = (c < 64) ? c : c - 64;
      r0 = *(const float4*)&Wb[(tk * 4 + 0) * 64 + cc];
      r1 = *(const float4*)&Wb[(tk * 4 + 1) * 64 + cc];
      r2 = *(const float4*)&Wb[(tk * 4 + 2) * 64 + cc];
      r3 = *(const float4*)&Wb[(tk * 4 + 3) * 64 + cc];
    } else {
      r0 = *(const float4*)&W0[(tk * 4 + 0) * 128 + tc * 4];
      r1 = *(const float4*)&W0[(tk * 4 + 1) * 128 + tc * 4];
      r2 = *(const float4*)&W0[(tk * 4 + 2) * 128 + tc * 4];
      r3 = *(const float4*)&W0[(tk * 4 + 3) * 128 + tc * 4];
    }
    const float* p0 = (const float*)&r0;
    const float* p1 = (const float*)&r1;
    const float* p2 = (const float*)&r2;
    const float* p3 = (const float*)&r3;
    #pragma unroll
    for (int j = 0; j < 4; ++j) {
      uint lo = (uint)f2bf(p0[j]) | ((uint)f2bf(p1[j]) << 16);
      uint hi = (uint)f2bf(p2[j]) | ((uint)f2bf(p3[j]) << 16);
      *(uint2*)&sWt[(tc * 4 + j) * PK + tk * 4] = make_uint2(lo, hi);
    }
  }
  __syncthreads();

  const int w = tid >> 6;
  const int lane = tid & 63;
  const int l16 = lane & 15, q = lane >> 4;
  const int row0 = blockIdx.x * 128 + w * 32;

  f32x4 acc[2][8];
  #pragma unroll
  for (int mt = 0; mt < 2; ++mt)
    #pragma unroll
    for (int nt = 0; nt < 8; ++nt)
      acc[mt][nt] = (f32x4){0.f, 0.f, 0.f, 0.f};

  for (int ks = 0; ks < 4; ++ks) {
    const int kbase = ks * 32 + q * 8;
    short8 afrag[2];
    #pragma unroll
    for (int mt = 0; mt < 2; ++mt) {
      int row = row0 + mt * 16 + l16;
      float av[8] = {0.f,0.f,0.f,0.f,0.f,0.f,0.f,0.f};
      if (row < n) {
        if constexpr (FUSED) {
          uint4 zw = *(const uint4*)&Az[(size_t)row * 64 + (kbase >> 1)];
          float zv[8] = { bf_lo(zw.x), bf_hi(zw.x), bf_lo(zw.y), bf_hi(zw.y),
                          bf_lo(zw.z), bf_hi(zw.z), bf_lo(zw.w), bf_hi(zw.w) };
          float4 sc0 = *(const float4*)&scale[kbase];
          float4 sc1 = *(const float4*)&scale[kbase + 4];
          float4 sh0 = *(const float4*)&shift[kbase];
          float4 sh1 = *(const float4*)&shift[kbase + 4];
          const float* scp = (const float*)&sc0;  // contiguous? no — handle in pairs
          float scv[8] = { sc0.x, sc0.y, sc0.z, sc0.w, sc1.x, sc1.y, sc1.z, sc1.w };
          float shv[8] = { sh0.x, sh0.y, sh0.z, sh0.w, sh1.x, sh1.y, sh1.z, sh1.w };
          const float* Xr = xres + (size_t)row * 128 + kbase;
          float4 x0 = *(const float4*)&Xr[0];
          float4 x1 = *(const float4*)&Xr[4];
          float xv[8] = { x0.x, x0.y, x0.z, x0.w, x1.x, x1.y, x1.z, x1.w };
          (void)scp;
          #pragma unroll
          for (int j = 0; j < 8; ++j) {
            float u = fmaf(zv[j], scv[j], shv[j]);
            u = u >= 0.f ? u : SLOPE * u;
            av[j] = u + xv[j];
          }
          if constexpr (WRITEX) {
            float* Xo = xout + (size_t)row * 128 + kbase;
            *(float4*)&Xo[0] = make_float4(av[0], av[1], av[2], av[3]);
            *(float4*)&Xo[4] = make_float4(av[4], av[5], av[6], av[7]);
          }
        } else {
          const float* Ar = Af + (size_t)row * 128 + kbase;
          float4 a0 = *(const float4*)&Ar[0];
          float4 a1 = *(const float4*)&Ar[4];
          av[0]=a0.x; av[1]=a0.y; av[2]=a0.z; av[3]=a0.w;
          av[4]=a1.x; av[5]=a1.y; av[6]=a1.z; av[7]=a1.w;
        }
      }
      short8 af;
      #pragma unroll
      for (int j = 0; j < 8; ++j) af[j] = (short)f2bf(av[j]);
      afrag[mt] = af;
    }
    #pragma unroll
    for (int nt = 0; nt < 8; ++nt) {
      short8 bfrag = *(const short8*)&sWt[(nt * 16 + l16) * PK + kbase];
      acc[0][nt] = __builtin_amdgcn_mfma_f32_16x16x32_bf16(afrag[0], bfrag, acc[0][nt], 0, 0, 0);
      acc[1][nt] = __builtin_amdgcn_mfma_f32_16x16x32_bf16(afrag[1], bfrag, acc[1][nt], 0, 0, 0);
    }
  }
  #pragma unroll
  for (int mt = 0; mt < 2; ++mt) {
    int rbase = row0 + mt * 16 + q * 4;
    #pragma unroll
    for (int nt = 0; nt < 8; ++nt) {
      int col = nt * 16 + l16;
      #pragma unroll
      for (int r = 0; r < 4; ++r) {
        int row = rbase + r;
        if (row < n) Cbf[(size_t)row * 128 + col] = f2bf(acc[mt][nt][r]);
      }
    }
  }
}

// ---------- gather propagate + fused BN partial stats; z out bf16-packed ----------
__global__ __launch_bounds__(256) void gather_layer(const int* __restrict__ ptr,
    const int2* __restrict__ csr, const uint* __restrict__ ybf,
    const float* __restrict__ b, const float* __restrict__ dinv,
    uint* __restrict__ zbf, float* __restrict__ psum, float* __restrict__ psq, int n) {
  const int tid = threadIdx.x;
  const int lane = tid & 63, wv = tid >> 6;
  float2 bb = *(const float2*)&b[lane * 2];
  float sx = 0.f, sy = 0.f, qx = 0.f, qy = 0.f;
  const int wstride = gridDim.x * 4;
  for (int w = blockIdx.x * 4 + wv; w < n; w += wstride) {
    float dv = dinv[w], c0 = dv * dv;
    uint yv = ybf[(size_t)w * 64 + lane];
    float ax = fmaf(c0, bf_lo(yv), bb.x);
    float ay = fmaf(c0, bf_hi(yv), bb.y);
    int j = ptr[w], end = ptr[w + 1];
    if ((j & 1) && j < end) {          // peel to 16B-align csr
      int2 e = csr[j];
      uint v = ybf[(size_t)e.x * 64 + lane];
      float c = __int_as_float(e.y);
      ax = fmaf(c, bf_lo(v), ax); ay = fmaf(c, bf_hi(v), ay);
      ++j;
    }
    for (; j + 3 < end; j += 4) {
      int4 p0 = *(const int4*)&csr[j];
      int4 p1 = *(const int4*)&csr[j + 2];
      uint v0 = ybf[(size_t)p0.x * 64 + lane];
      uint v1 = ybf[(size_t)p0.z * 64 + lane];
      uint v2 = ybf[(size_t)p1.x * 64 + lane];
      uint v3 = ybf[(size_t)p1.z * 64 + lane];
      float c0_ = __int_as_float(p0.y), c1_ = __int_as_float(p0.w);
      float c2_ = __int_as_float(p1.y), c3_ = __int_as_float(p1.w);
      ax = fmaf(c0_, bf_lo(v0), ax); ay = fmaf(c0_, bf_hi(v0), ay);
      ax = fmaf(c1_, bf_lo(v1), ax); ay = fmaf(c1_, bf_hi(v1), ay);
      ax = fmaf(c2_, bf_lo(v2), ax); ay = fmaf(c2_, bf_hi(v2), ay);
      ax = fmaf(c3_, bf_lo(v3), ax); ay = fmaf(c3_, bf_hi(v3), ay);
    }
    for (; j < end; ++j) {
      int2 e = csr[j];
      uint v = ybf[(size_t)e.x * 64 + lane];
      float c = __int_as_float(e.y);
      ax = fmaf(c, bf_lo(v), ax); ay = fmaf(c, bf_hi(v), ay);
    }
    zbf[(size_t)w * 64 + lane] = pack2bf(ax, ay);
    sx += ax; sy += ay;
    qx = fmaf(ax, ax, qx); qy = fmaf(ay, ay, qy);
  }
  __shared__ float red[4][64];
  red[wv][lane] = sx; __syncthreads();
  if (wv == 0) psum[(size_t)blockIdx.x * 128 + lane * 2] =
      red[0][lane] + red[1][lane] + red[2][lane] + red[3][lane];
  __syncthreads();
  red[wv][lane] = sy; __syncthreads();
  if (wv == 0) psum[(size_t)blockIdx.x * 128 + lane * 2 + 1] =
      red[0][lane] + red[1][lane] + red[2][lane] + red[3][lane];
  __syncthreads();
  red[wv][lane] = qx; __syncthreads();
  if (wv == 0) psq[(size_t)blockIdx.x * 128 + lane * 2] =
      red[0][lane] + red[1][lane] + red[2][lane] + red[3][lane];
  __syncthreads();
  red[wv][lane] = qy; __syncthreads();
  if (wv == 0) psq[(size_t)blockIdx.x * 128 + lane * 2 + 1] =
      red[0][lane] + red[1][lane] + red[2][lane] + red[3][lane];
}

// ---------- heads gather: cols 0-63 -> mu, 64-127 -> logvar (f32 out) ----------
__global__ __launch_bounds__(256) void gather_heads(const int* __restrict__ ptr,
    const int2* __restrict__ csr, const uint* __restrict__ ybf,
    const float* __restrict__ bmu, const float* __restrict__ blv,
    const float* __restrict__ dinv, float* __restrict__ out, int n) {
  int w = (blockIdx.x * 256 + threadIdx.x) >> 6;
  if (w >= n) return;
  int lane = threadIdx.x & 63;
  int col = lane * 2;
  float* obase; const float* bias; int cc;
  if (col < 64) { obase = out; bias = bmu; cc = col; }
  else { obase = out + (size_t)n * 64; bias = blv; cc = col - 64; }
  float dv = dinv[w], c0 = dv * dv;
  uint yv = ybf[(size_t)w * 64 + lane];
  float ax = fmaf(c0, bf_lo(yv), bias[cc]);
  float ay = fmaf(c0, bf_hi(yv), bias[cc + 1]);
  int j = ptr[w], end = ptr[w + 1];
  if ((j & 1) && j < end) {
    int2 e = csr[j];
    uint v = ybf[(size_t)e.x * 64 + lane];
    float c = __int_as_float(e.y);
    ax = fmaf(c, bf_lo(v), ax); ay = fmaf(c, bf_hi(v), ay);
    ++j;
  }
  for (; j + 3 < end; j += 4) {
    int4 p0 = *(const int4*)&csr[j];
    int4 p1 = *(const int4*)&csr[j + 2];
    uint v0 = ybf[(size_t)p0.x * 64 + lane];
    uint v1 = ybf[(size_t)p0.z * 64 + lane];
    uint v2 = ybf[(size_t)p1.x * 64 + lane];
    uint v3 = ybf[(size_t)p1.z * 64 + lane];
    float c0_ = __int_as_float(p0.y), c1_ = __int_as_float(p0.w);
    float c2_ = __int_as_float(p1.y), c3_ = __int_as_float(p1.w);
    ax = fmaf(c0_, bf_lo(v0), ax); ay = fmaf(c0_, bf_hi(v0), ay);
    ax = fmaf(c1_, bf_lo(v1), ax); ay = fmaf(c1_, bf_hi(v1), ay);
    ax = fmaf(c2_, bf_lo(v2), ax); ay = fmaf(c2_, bf_hi(v2), ay);
    ax = fmaf(c3_, bf_lo(v3), ax); ay = fmaf(c3_, bf_hi(v3), ay);
  }
  for (; j < end; ++j) {
    int2 e = csr[j];
    uint v = ybf[(size_t)e.x * 64 + lane];
    float c = __int_as_float(e.y);
    ax = fmaf(c, bf_lo(v), ax); ay = fmaf(c, bf_hi(v), ay);
  }
  *(float2*)&obase[(size_t)w * 64 + cc] = make_float2(ax, ay);
}

// ---------- BN finalize: 128 blocks (one per channel) ----------
__global__ __launch_bounds__(256) void bnfin_kernel(const float* __restrict__ psum,
    const float* __restrict__ psq, const float* __restrict__ gamma,
    const float* __restrict__ beta, float* __restrict__ scale,
    float* __restrict__ shift, int n, int nb) {
  const int c = blockIdx.x;
  const int tid = threadIdx.x;
  float s = 0.f, s2 = 0.f;
  for (int b = tid; b < nb; b += 256) {
    s += psum[(size_t)b * 128 + c];
    s2 += psq[(size_t)b * 128 + c];
  }
  #pragma unroll
  for (int ofs = 32; ofs; ofs >>= 1) {
    s += __shfl_down(s, ofs, 64);
    s2 += __shfl_down(s2, ofs, 64);
  }
  __shared__ float ws[4], wq[4];
  if ((tid & 63) == 0) { ws[tid >> 6] = s; wq[tid >> 6] = s2; }
  __syncthreads();
  if (tid == 0) {
    float S = ws[0] + ws[1] + ws[2] + ws[3];
    float Q = wq[0] + wq[1] + wq[2] + wq[3];
    float mean = S / (float)n;
    float var = Q / (float)n - mean * mean;
    float inv = rsqrtf(var + EPS);
    float sc = gamma[c] * inv;
    scale[c] = sc;
    shift[c] = beta[c] - mean * sc;
  }
}

extern "C" void kernel_launch(void* const* d_in, const int* in_sizes, int n_in,
                              void* d_out, int out_size, void* d_ws, size_t ws_size,
                              hipStream_t stream) {
  const float* x     = (const float*)d_in[0];
  const int*   ei    = (const int*)d_in[1];
  const float* Ws    = (const float*)d_in[2];
  const float* bs    = (const float*)d_in[3];
  const float* Wmu   = (const float*)d_in[4];
  const float* bmu   = (const float*)d_in[5];
  const float* Wlv   = (const float*)d_in[6];
  const float* blv   = (const float*)d_in[7];
  const float* gamma = (const float*)d_in[8];
  const float* beta  = (const float*)d_in[9];
  float* out = (float*)d_out;

  const int n = in_sizes[0] / 128;
  const int E = in_sizes[1] / 2;
  const int* srcI = ei;
  const int* dstI = ei + E;
  const int nb = cdiv(n, 256);

  char* wsp = (char*)d_ws;
  size_t off = 0;
  auto alloc = [&](size_t bytes) -> void* {
    void* p = wsp + off;
    off += (bytes + 255) & ~(size_t)255;
    return p;
  };
  int*    degi  = (int*)alloc((size_t)n * 4);
  float*  dinv  = (float*)alloc((size_t)n * 4);
  int*    ptr   = (int*)alloc((size_t)(n + 1) * 4);
  int*    fillc = (int*)alloc((size_t)n * 4);
  int*    bsum  = (int*)alloc((size_t)nb * 4);
  int*    bofs  = (int*)alloc((size_t)nb * 4);
  int2*   csr   = (int2*)alloc((size_t)E * 8);
  ushort* ybf   = (ushort*)alloc((size_t)n * 128 * 2);
  uint*   zbf   = (uint*)alloc((size_t)n * 64 * 4);
  float*  xbuf  = (float*)alloc((size_t)n * 128 * 4);
  float*  psum  = (float*)alloc((size_t)GATHER_BLOCKS * 128 * 4);
  float*  psq   = (float*)alloc((size_t)GATHER_BLOCKS * 128 * 4);
  float*  scale = (float*)alloc(128 * 4);
  float*  shift = (float*)alloc(128 * 4);
  (void)n_in; (void)out_size; (void)ws_size;

  hipMemsetAsync(degi, 0, (size_t)n * 4, stream);
  hipMemsetAsync(fillc, 0, (size_t)n * 4, stream);
  deg_kernel<<<cdiv(E, 256), 256, 0, stream>>>(dstI, degi, E);
  dinv_kernel<<<cdiv(n, 256), 256, 0, stream>>>(degi, dinv, n);
  bsum_kernel<<<nb, 256, 0, stream>>>(degi, bsum, n);
  bscan_kernel<<<1, 256, 0, stream>>>(bsum, bofs, ptr + n, nb);
  ptr_kernel<<<nb, 256, 0, stream>>>(degi, bofs, ptr, n);
  fill_kernel<<<cdiv(E, 256), 256, 0, stream>>>(srcI, dstI, dinv, ptr, fillc, csr, E);

  const int ggrid = cdiv(n, 128);
  const int wgrid = cdiv((long)n * 64, 256);

  // layer 0
  mfma_gemm<false, false, false><<<ggrid, 256, 0, stream>>>(
      x, nullptr, nullptr, nullptr, nullptr, nullptr, Ws, nullptr, ybf, n);
  gather_layer<<<GATHER_BLOCKS, 256, 0, stream>>>(ptr, csr, (const uint*)ybf, bs, dinv, zbf, psum, psq, n);
  bnfin_kernel<<<128, 256, 0, stream>>>(psum, psq, gamma, beta, scale, shift, n, GATHER_BLOCKS);
  // layer 1 (fused BN+leaky+res with xres=x, writes xbuf)
  mfma_gemm<true, true, false><<<ggrid, 256, 0, stream>>>(
      nullptr, zbf, scale, shift, x, xbuf, Ws + 16384, nullptr, ybf, n);
  gather_layer<<<GATHER_BLOCKS, 256, 0, stream>>>(ptr, csr, (const uint*)ybf, bs + 128, dinv, zbf, psum, psq, n);
  bnfin_kernel<<<128, 256, 0, stream>>>(psum, psq, gamma, beta, scale, shift, n, GATHER_BLOCKS);
  // layer 2 (xres=xbuf, in-place update)
  mfma_gemm<true, true, false><<<ggrid, 256, 0, stream>>>(
      nullptr, zbf, scale, shift, xbuf, xbuf, Ws + 32768, nullptr, ybf, n);
  gather_layer<<<GATHER_BLOCKS, 256, 0, stream>>>(ptr, csr, (const uint*)ybf, bs + 256, dinv, zbf, psum, psq, n);
  bnfin_kernel<<<128, 256, 0, stream>>>(psum, psq, gamma, beta, scale, shift, n, GATHER_BLOCKS);
  // heads: one GEMM with W = [Wmu | Wlv], one gather writing both outputs
  mfma_gemm<true, false, true><<<ggrid, 256, 0, stream>>>(
      nullptr, zbf, scale, shift, xbuf, nullptr, Wmu, Wlv, ybf, n);
  gather_heads<<<wgrid, 256, 0, stream>>>(ptr, csr, (const uint*)ybf, bmu, blv, dinv, out, n);
}